// Round 1
// baseline (280.905 us; speedup 1.0000x reference)
//
#include <hip/hip_runtime.h>

// ---------------------------------------------------------------------------
// AttentionActPrune — full MHA forward. B=4, S=2048, H=16, DH=64, D=1024.
// fp32 in/out; threshold 2% of max|ref| -> bf16 MFMA compute.
// Pipeline: cvt_all -> merged QKV GEMM (Q pre-scaled by softmax const; V ->
// Vt[bh][d][s] transposed epilogue) -> flash-attn (kv-permuted K staging ->
// K=32 PV MFMAs, register P, XCD swizzle, ping-pong LDS) -> GEMM out.
// ---------------------------------------------------------------------------

typedef __bf16 bf16;
typedef __bf16 bf16x8 __attribute__((ext_vector_type(8)));
typedef __bf16 bf16x4 __attribute__((ext_vector_type(4)));
typedef float  floatx4 __attribute__((ext_vector_type(4)));

#define NB   4
#define SEQ  2048
#define NH   16
#define DH   64
#define DIM  1024
#define MTOT (NB * SEQ)   // 8192

#define CEXP 0.18033688f   // (1/sqrt(DH)) * log2(e), folded into Q

__device__ __forceinline__ floatx4 zero4() {
    floatx4 z; z[0] = 0.f; z[1] = 0.f; z[2] = 0.f; z[3] = 0.f; return z;
}

__device__ __forceinline__ void load_lds16(const bf16* g, bf16* l) {
    __builtin_amdgcn_global_load_lds(
        (__attribute__((address_space(1))) void*)g,
        (__attribute__((address_space(3))) void*)l,
        16, 0, 0);
}

// ---------------------------------------------------------------------------
// fp32 -> bf16 converts: X (MD elems) then [Wq;Wk;Wv;Wo] (4*DD) in one grid.
// ---------------------------------------------------------------------------
__global__ __launch_bounds__(256) void cvt_all(const float* __restrict__ X,
                                               const float* __restrict__ w0,
                                               const float* __restrict__ w1,
                                               const float* __restrict__ w2,
                                               const float* __restrict__ w3,
                                               bf16* __restrict__ Xb,
                                               bf16* __restrict__ Wb) {
    const size_t MD = (size_t)MTOT * DIM;
    const size_t DD = (size_t)DIM * DIM;   // 2^20
    size_t i = ((size_t)blockIdx.x * 256 + threadIdx.x) * 4;
    float4 f; bf16* dst;
    if (i < MD) {
        f = *(const float4*)(X + i);
        dst = Xb + i;
    } else {
        size_t off = i - MD;
        int w = (int)(off >> 20);
        size_t wi = off & (DD - 1);
        const float* ws = (w == 0) ? w0 : (w == 1) ? w1 : (w == 2) ? w2 : w3;
        f = *(const float4*)(ws + wi);
        dst = Wb + off;
    }
    bf16x4 o;
    o[0] = (bf16)f.x; o[1] = (bf16)f.y; o[2] = (bf16)f.z; o[3] = (bf16)f.w;
    *(bf16x4*)dst = o;
}

// ---------------------------------------------------------------------------
// Merged QKV GEMM. W = [Wq;Wk;Wv;Wo] rows contiguous. blockIdx.x: 0-7 Q,
// 8-15 K, 16-23 V(transposed epilogue). C[m][n]=sum_k A[m][k]W[n][k]+b[n].
// Q output (sel==0) additionally scaled by CEXP (softmax fold).
// ---------------------------------------------------------------------------
__global__ __launch_bounds__(256) void gemm_qkv(const bf16* __restrict__ A,
                                                const bf16* __restrict__ W,
                                                const float* __restrict__ bq,
                                                const float* __restrict__ bk,
                                                const float* __restrict__ bv,
                                                bf16* __restrict__ Qo,
                                                bf16* __restrict__ Ko,
                                                bf16* __restrict__ Vt) {
    __shared__ __align__(16) bf16 As[128 * 32];
    __shared__ __align__(16) bf16 Bs[128 * 32];
    __shared__ __align__(16) bf16 Ts[64 * 136];

    const int tid  = threadIdx.x;
    const int wave = tid >> 6, lane = tid & 63;
    const int quad = lane >> 4, l16 = lane & 15;
    const int sel = blockIdx.x >> 3;            // 0=Q 1=K 2=V
    const int nt  = blockIdx.x & 7;
    const int m0 = blockIdx.y * 128, n0 = nt * 128;
    const int wm = (wave & 1) * 64, wn = (wave >> 1) * 64;
    const bf16* Wsel = W + (size_t)(sel * DIM + n0) * DIM;
    const float* bias = (sel == 0) ? bq : (sel == 1) ? bk : bv;
    const float scale = (sel == 0) ? CEXP : 1.0f;

    floatx4 acc[4][4];
#pragma unroll
    for (int mi = 0; mi < 4; mi++)
#pragma unroll
        for (int ni = 0; ni < 4; ni++) acc[mi][ni] = zero4();

    for (int k0 = 0; k0 < DIM; k0 += 32) {
        __syncthreads();
#pragma unroll
        for (int i = 0; i < 2; i++) {
            const int cb = wave * 128 + i * 64;
            const int c  = cb + lane;
            const int row = c >> 2;
            const int kc  = (c & 3) * 8;
            load_lds16(A + (size_t)(m0 + row) * DIM + k0 + kc, &As[cb * 8]);
            load_lds16(Wsel + (size_t)row * DIM + k0 + kc, &Bs[cb * 8]);
        }
        __syncthreads();

        bf16x8 af[4], bfr[4];
#pragma unroll
        for (int mi = 0; mi < 4; mi++)
            af[mi] = *(const bf16x8*)&As[(wm + mi * 16 + l16) * 32 + quad * 8];
#pragma unroll
        for (int ni = 0; ni < 4; ni++)
            bfr[ni] = *(const bf16x8*)&Bs[(wn + ni * 16 + l16) * 32 + quad * 8];
#pragma unroll
        for (int mi = 0; mi < 4; mi++)
#pragma unroll
            for (int ni = 0; ni < 4; ni++)
                acc[mi][ni] = __builtin_amdgcn_mfma_f32_16x16x32_bf16(
                    af[mi], bfr[ni], acc[mi][ni], 0, 0, 0);
    }

    if (sel < 2) {
        bf16* C = (sel == 0) ? Qo : Ko;
#pragma unroll
        for (int mi = 0; mi < 4; mi++) {
            const int rbase = m0 + wm + mi * 16 + quad * 4;
#pragma unroll
            for (int ni = 0; ni < 4; ni++) {
                const int col = n0 + wn + ni * 16 + l16;
                const float bval = bias[col];
#pragma unroll
                for (int i = 0; i < 4; i++)
                    C[(size_t)(rbase + i) * DIM + col] =
                        (bf16)((acc[mi][ni][i] + bval) * scale);
            }
        }
    } else {
        // write Vt[(b*NH+h)][d][s], via LDS transpose (two 64-col halves)
        const int b  = blockIdx.y >> 4;
        const int s0 = (blockIdx.y & 15) * 128;
#pragma unroll
        for (int r = 0; r < 2; r++) {
            __syncthreads();
            if ((wave >> 1) == r) {
#pragma unroll
                for (int mi = 0; mi < 4; mi++) {
                    const int m_l = wm + mi * 16 + quad * 4;
#pragma unroll
                    for (int ni = 0; ni < 4; ni++) {
                        const int n_loc = ni * 16 + l16;
                        const float bval = bias[n0 + 64 * r + n_loc];
#pragma unroll
                        for (int i = 0; i < 4; i++)
                            Ts[n_loc * 136 + m_l + i] = (bf16)(acc[mi][ni][i] + bval);
                    }
                }
            }
            __syncthreads();
            const int hh = 2 * nt + r;
            bf16* obase = Vt + ((size_t)(b * NH + hh) * DH) * SEQ + s0;
#pragma unroll
            for (int p = 0; p < 4; p++) {
                const int chunk = p * 256 + tid;
                const int row = chunk >> 4, c0 = (chunk & 15) * 8;
                bf16x8 v = *(const bf16x8*)&Ts[row * 136 + c0];
                *(bf16x8*)(obase + (size_t)row * SEQ + c0) = v;
            }
        }
    }
}

// ---------------------------------------------------------------------------
// Out-projection GEMM (fp32 out), 128x128 tiles.
// ---------------------------------------------------------------------------
__global__ __launch_bounds__(256) void gemm_out(const bf16* __restrict__ A,
                                                const bf16* __restrict__ W,
                                                const float* __restrict__ bias,
                                                float* __restrict__ C) {
    __shared__ __align__(16) bf16 As[128 * 32];
    __shared__ __align__(16) bf16 Bs[128 * 32];

    const int tid  = threadIdx.x;
    const int wave = tid >> 6, lane = tid & 63;
    const int quad = lane >> 4, l16 = lane & 15;
    const int m0 = blockIdx.y * 128, n0 = blockIdx.x * 128;
    const int wm = (wave & 1) * 64, wn = (wave >> 1) * 64;

    floatx4 acc[4][4];
#pragma unroll
    for (int mi = 0; mi < 4; mi++)
#pragma unroll
        for (int ni = 0; ni < 4; ni++) acc[mi][ni] = zero4();

    for (int k0 = 0; k0 < DIM; k0 += 32) {
        __syncthreads();
#pragma unroll
        for (int i = 0; i < 2; i++) {
            const int cb = wave * 128 + i * 64;
            const int c  = cb + lane;
            const int row = c >> 2;
            const int kc  = (c & 3) * 8;
            load_lds16(A + (size_t)(m0 + row) * DIM + k0 + kc, &As[cb * 8]);
            load_lds16(W + (size_t)(n0 + row) * DIM + k0 + kc, &Bs[cb * 8]);
        }
        __syncthreads();

        bf16x8 af[4], bfr[4];
#pragma unroll
        for (int mi = 0; mi < 4; mi++)
            af[mi] = *(const bf16x8*)&As[(wm + mi * 16 + l16) * 32 + quad * 8];
#pragma unroll
        for (int ni = 0; ni < 4; ni++)
            bfr[ni] = *(const bf16x8*)&Bs[(wn + ni * 16 + l16) * 32 + quad * 8];
#pragma unroll
        for (int mi = 0; mi < 4; mi++)
#pragma unroll
            for (int ni = 0; ni < 4; ni++)
                acc[mi][ni] = __builtin_amdgcn_mfma_f32_16x16x32_bf16(
                    af[mi], bfr[ni], acc[mi][ni], 0, 0, 0);
    }

#pragma unroll
    for (int mi = 0; mi < 4; mi++) {
        const int rbase = m0 + wm + mi * 16 + quad * 4;
#pragma unroll
        for (int ni = 0; ni < 4; ni++) {
            const int col = n0 + wn + ni * 16 + l16;
            const float bval = bias[col];
#pragma unroll
            for (int i = 0; i < 4; i++)
                C[(size_t)(rbase + i) * DIM + col] = acc[mi][ni][i] + bval;
        }
    }
}

// ---------------------------------------------------------------------------
// Flash attention: 4-wave blocks = 128 q rows of one (b,h), 32 q/wave.
// XCD-swizzled grid (L2-resident K/V: round-10 FETCH 139->25 MB).
// NEW: K rows are staged PERMUTED within each 32-kv window:
//   LDS row r (r4 = r&15): kv = 32*(r>>5) + 8*(r4>>2) + 4*(r>=16 in window) + (r4&3)
// so the two 16-row S^T C-layouts concatenate into exactly the A-fragment
// (k=quad*8+j) of mfma_f32_16x16x32_bf16 -> PV runs at K=32:
// 28 MFMAs/tile (was 56), V frags are single b128 reads (was 2x b64).
// V staged in natural [d][s] order (B-frag k=quad*8+j = 8 contiguous s).
// Per-window batching: 4 K-frag reads -> 1 wait -> 4 QK -> 8 exp2 ->
// 4 V-frag b128 -> 10 PV/ones. Q pre-scaled by CEXP -> P = exp2(z).
// ---------------------------------------------------------------------------
__global__ __launch_bounds__(256, 4) void attn_kernel(const bf16* __restrict__ Q,
                                                      const bf16* __restrict__ K,
                                                      const bf16* __restrict__ Vt,
                                                      bf16* __restrict__ Ctx) {
    __shared__ __align__(16) bf16 Ks[2][64 * 64];  // swizzled, kv-permuted
    __shared__ __align__(16) bf16 Vs[2][64 * 64];  // swizzled, natural order

    const int tid  = threadIdx.x;
    const int wave = tid >> 6, lane = tid & 63;
    const int quad = lane >> 4, l16 = lane & 15;
    // XCD-aware swizzle (1024 blocks, 8 XCDs)
    const int xcd = blockIdx.x & 7;
    const int j   = blockIdx.x >> 3;        // 0..127
    const int bh  = xcd * 8 + (j >> 4);     // b*NH + h
    const int qb  = j & 15;                 // 128-row q block
    const int b   = bh >> 4, h = bh & 15;

    const size_t base_bh = (size_t)b * SEQ * DIM + (size_t)h * DH;
    const size_t base_v  = (size_t)bh * DH * SEQ;
    const int qt = qb * 128 + wave * 32;    // wave's 32 q rows

    // Q frags (B-operand of swapped QK MFMA): 2 m-subtiles x 2 d-halves
    bf16x8 aq[2][2];
#pragma unroll
    for (int m = 0; m < 2; m++) {
        const bf16* qp = Q + base_bh + (size_t)(qt + m * 16 + l16) * DIM + quad * 8;
        aq[m][0] = *(const bf16x8*)qp;
        aq[m][1] = *(const bf16x8*)(qp + 32);
    }

    // staging addresses (kv-invariant): chunk ids sc, sc+64 per array
    const int sc = wave * 128 + lane;
    int srow[2], scol[2];
    srow[0] = sc >> 3;        srow[1] = (sc + 64) >> 3;
    scol[0] = (sc & 7) ^ (srow[0] & 7);
    scol[1] = ((sc + 64) & 7) ^ (srow[1] & 7);
    // K permuted kv offset for a physical row r
    auto kvloc = [](int r) {
        const int w = r >> 5, rw = r & 31, r4 = rw & 15;
        return w * 32 + ((rw >> 4) << 2) + ((r4 >> 2) << 3) + (r4 & 3);
    };
    const bf16* kga = K + base_bh + (size_t)kvloc(srow[0]) * DIM + scol[0] * 8;
    const bf16* kgb = K + base_bh + (size_t)kvloc(srow[1]) * DIM + scol[1] * 8;
    const bf16* vga = Vt + base_v + (size_t)srow[0] * SEQ + scol[0] * 8;
    const bf16* vgb = Vt + base_v + (size_t)srow[1] * SEQ + scol[1] * 8;
    const int ldsa = (wave * 128) * 8, ldsb = (wave * 128 + 64) * 8;

    // LDS read offsets (kv-invariant): K frags per group g, V per (w,dt)
    int koa[4], kob[4], vo[2][4];
#pragma unroll
    for (int g = 0; g < 4; g++) {
        const int krow = g * 16 + l16;
        koa[g] = (krow * 8 + (quad ^ (krow & 7))) * 8;
        kob[g] = (krow * 8 + ((4 + quad) ^ (krow & 7))) * 8;
    }
#pragma unroll
    for (int w = 0; w < 2; w++)
#pragma unroll
        for (int dt = 0; dt < 4; dt++) {
            const int d = dt * 16 + l16;
            vo[w][dt] = d * 64 + ((4 * w + quad) ^ (d & 7)) * 8;
        }

    bf16x8 ones8;
#pragma unroll
    for (int i = 0; i < 8; i++) ones8[i] = (bf16)1.0f;

    floatx4 acc[2][4], accl[2];
#pragma unroll
    for (int m = 0; m < 2; m++) {
        accl[m] = zero4();
#pragma unroll
        for (int dt = 0; dt < 4; dt++) acc[m][dt] = zero4();
    }

    // prologue: stage tile 0 into buffer 0
    load_lds16(kga, &Ks[0][ldsa]);
    load_lds16(kgb, &Ks[0][ldsb]);
    load_lds16(vga, &Vs[0][ldsa]);
    load_lds16(vgb, &Vs[0][ldsb]);

    for (int it = 0; it < SEQ / 64; it++) {
        __syncthreads();  // drains staging issued last iter; readers done
        const int cur = it & 1;
        if (it + 1 < SEQ / 64) {
            const int nxt = cur ^ 1;
            const size_t kvn = (size_t)(it + 1) * 64;
            load_lds16(kga + kvn * DIM, &Ks[nxt][ldsa]);
            load_lds16(kgb + kvn * DIM, &Ks[nxt][ldsb]);
            load_lds16(vga + kvn, &Vs[nxt][ldsa]);
            load_lds16(vgb + kvn, &Vs[nxt][ldsb]);
        }

#pragma unroll
        for (int w = 0; w < 2; w++) {
            // K frags for groups 2w (even: k=8q..8q+3), 2w+1 (odd: 8q+4..7)
            const bf16x8 ke0 = *(const bf16x8*)&Ks[cur][koa[2 * w]];
            const bf16x8 ke1 = *(const bf16x8*)&Ks[cur][kob[2 * w]];
            const bf16x8 ko0 = *(const bf16x8*)&Ks[cur][koa[2 * w + 1]];
            const bf16x8 ko1 = *(const bf16x8*)&Ks[cur][kob[2 * w + 1]];
            bf16x8 pw[2];
#pragma unroll
            for (int m = 0; m < 2; m++) {
                floatx4 sa = zero4(), sb = zero4();
                sa = __builtin_amdgcn_mfma_f32_16x16x32_bf16(ke0, aq[m][0], sa, 0, 0, 0);
                sa = __builtin_amdgcn_mfma_f32_16x16x32_bf16(ke1, aq[m][1], sa, 0, 0, 0);
                sb = __builtin_amdgcn_mfma_f32_16x16x32_bf16(ko0, aq[m][0], sb, 0, 0, 0);
                sb = __builtin_amdgcn_mfma_f32_16x16x32_bf16(ko1, aq[m][1], sb, 0, 0, 0);
                bf16x8 p;
#pragma unroll
                for (int i = 0; i < 4; i++) {
                    p[i]     = (bf16)__builtin_amdgcn_exp2f(sa[i]);
                    p[4 + i] = (bf16)__builtin_amdgcn_exp2f(sb[i]);
                }
                pw[m] = p;
            }
            // V frags: b128, natural kv order
            bf16x8 vf[4];
#pragma unroll
            for (int dt = 0; dt < 4; dt++)
                vf[dt] = *(const bf16x8*)&Vs[cur][vo[w][dt]];
#pragma unroll
            for (int m = 0; m < 2; m++) {
#pragma unroll
                for (int dt = 0; dt < 4; dt++)
                    acc[m][dt] = __builtin_amdgcn_mfma_f32_16x16x32_bf16(
                        pw[m], vf[dt], acc[m][dt], 0, 0, 0);
                accl[m] = __builtin_amdgcn_mfma_f32_16x16x32_bf16(
                    pw[m], ones8, accl[m], 0, 0, 0);
            }
        }
    }

    // store: O rows q=qt+m*16+quad*4+i, cols dt*16+l16
#pragma unroll
    for (int m = 0; m < 2; m++) {
        float inv[4];
#pragma unroll
        for (int i = 0; i < 4; i++) inv[i] = 1.0f / accl[m][i];
        bf16* cp = Ctx + base_bh + (size_t)(qt + m * 16 + quad * 4) * DIM + l16;
#pragma unroll
        for (int i = 0; i < 4; i++)
#pragma unroll
            for (int dt = 0; dt < 4; dt++)
                cp[(size_t)i * DIM + dt * 16] = (bf16)(acc[m][dt][i] * inv[i]);
    }
}

// ---------------------------------------------------------------------------
extern "C" void kernel_launch(void* const* d_in, const int* in_sizes, int n_in,
                              void* d_out, int out_size, void* d_ws, size_t ws_size,
                              hipStream_t stream) {
    const float* X  = (const float*)d_in[0];
    const float* Wq = (const float*)d_in[1];
    const float* bq = (const float*)d_in[2];
    const float* Wk = (const float*)d_in[3];
    const float* bk = (const float*)d_in[4];
    const float* Wv = (const float*)d_in[5];
    const float* bv = (const float*)d_in[6];
    const float* Wo = (const float*)d_in[7];
    const float* bo = (const float*)d_in[8];
    float* out = (float*)d_out;

    const size_t MD = (size_t)MTOT * DIM;
    const size_t DD = (size_t)DIM * DIM;

    bf16* Xb  = (bf16*)d_ws;     // X bf16; reused as ctx after attention
    bf16* Qb  = Xb + MD;
    bf16* Kb  = Qb + MD;
    bf16* Vtb = Kb + MD;         // V transposed [B*H][DH][SEQ]
    bf16* Wqb = Vtb + MD;        // [Wq;Wk;Wv;Wo] rows contiguous
    bf16* Wob = Wqb + 3 * DD;
    if (ws_size < (MD * 4 + DD * 4) * sizeof(bf16)) return;

    cvt_all<<<(int)((MD + 4 * DD) / 4 / 256), 256, 0, stream>>>(
        X, Wq, Wk, Wv, Wo, Xb, Wqb);

    gemm_qkv<<<dim3(24, MTOT / 128), 256, 0, stream>>>(Xb, Wqb, bq, bk, bv,
                                                       Qb, Kb, Vtb);

    // 1024 blocks x 256 threads: XCD-swizzled 64 (b,h) x 16 q-blocks
    attn_kernel<<<NB * NH * (SEQ / 128), 256, 0, stream>>>(Qb, Kb, Vtb, Xb);

    gemm_out<<<dim3(8, MTOT / 128), 256, 0, stream>>>(Xb, Wob, bo, out);
}

// Round 2
// 271.599 us; speedup vs baseline: 1.0343x; 1.0343x over previous
//
#include <hip/hip_runtime.h>

// ---------------------------------------------------------------------------
// AttentionActPrune — full MHA forward. B=4, S=2048, H=16, DH=64, D=1024.
// fp32 in/out; threshold 2% of max|ref| -> bf16 MFMA compute.
// Pipeline: cvt_all -> merged QKV GEMM (NEW: 256x256 tile, BK=32, 4-buffer
// 128KB LDS, counted-vmcnt deep pipeline, T2 swizzle, T5 setprio; V ->
// Vt[bh][d][s] via full-tile LDS transpose) -> flash-attn (unchanged) ->
// GEMM out (unchanged 128x128).
// ---------------------------------------------------------------------------

typedef __bf16 bf16;
typedef __bf16 bf16x8 __attribute__((ext_vector_type(8)));
typedef __bf16 bf16x4 __attribute__((ext_vector_type(4)));
typedef float  floatx4 __attribute__((ext_vector_type(4)));

#define NB   4
#define SEQ  2048
#define NH   16
#define DH   64
#define DIM  1024
#define MTOT (NB * SEQ)   // 8192

#define CEXP 0.18033688f   // (1/sqrt(DH)) * log2(e), folded into Q

__device__ __forceinline__ floatx4 zero4() {
    floatx4 z; z[0] = 0.f; z[1] = 0.f; z[2] = 0.f; z[3] = 0.f; return z;
}

__device__ __forceinline__ void load_lds16(const bf16* g, bf16* l) {
    __builtin_amdgcn_global_load_lds(
        (__attribute__((address_space(1))) void*)g,
        (__attribute__((address_space(3))) void*)l,
        16, 0, 0);
}

// ---------------------------------------------------------------------------
// fp32 -> bf16 converts: X (MD elems) then [Wq;Wk;Wv;Wo] (4*DD) in one grid.
// ---------------------------------------------------------------------------
__global__ __launch_bounds__(256) void cvt_all(const float* __restrict__ X,
                                               const float* __restrict__ w0,
                                               const float* __restrict__ w1,
                                               const float* __restrict__ w2,
                                               const float* __restrict__ w3,
                                               bf16* __restrict__ Xb,
                                               bf16* __restrict__ Wb) {
    const size_t MD = (size_t)MTOT * DIM;
    const size_t DD = (size_t)DIM * DIM;   // 2^20
    size_t i = ((size_t)blockIdx.x * 256 + threadIdx.x) * 4;
    float4 f; bf16* dst;
    if (i < MD) {
        f = *(const float4*)(X + i);
        dst = Xb + i;
    } else {
        size_t off = i - MD;
        int w = (int)(off >> 20);
        size_t wi = off & (DD - 1);
        const float* ws = (w == 0) ? w0 : (w == 1) ? w1 : (w == 2) ? w2 : w3;
        f = *(const float4*)(ws + wi);
        dst = Wb + off;
    }
    bf16x4 o;
    o[0] = (bf16)f.x; o[1] = (bf16)f.y; o[2] = (bf16)f.z; o[3] = (bf16)f.w;
    *(bf16x4*)dst = o;
}

// ---------------------------------------------------------------------------
// Merged QKV GEMM, 256x256 tiles, deep-pipelined.
//   grid: 384 blocks (XCD-bijective swizzle) = 32 m-tiles x {Q,K,V} x 4 n-tiles
//   512 threads = 8 waves (2 m x 4 n), wave tile 128x64, acc 8x4 frags.
//   K pipeline: BK=32, 4 LDS buffers (4x32KB = 128KB), stage tile t+3 during
//   tile t, s_waitcnt vmcnt(8) at tile end (2 K-tiles in flight, never 0).
//   2 phases/K-tile: {ds_read A[0..3]+B[0..3], stage A(t+3), bar, MFMA x16,
//   bar} then {ds_read A[4..7], stage B(t+3), bar, MFMA x16, vmcnt, bar}.
//   LDS swizzle: elem(row,q) = row*32 + (q ^ ((row>>1)&3))*8; staged linear
//   with inverse-permuted global source (both-sides rule).
//   Q output scaled by CEXP; V transposed to Vt[bh][d][s] via 128KB LDS
//   transpose (XOR-swizzled byte layout) after the K-loop.
// ---------------------------------------------------------------------------
#define QKV_TILE(T_, DO_STAGE_, WAITSTR_) do {                                 \
    const int bsel_ = (T_) & 3;                                                \
    const bf16* bA_ = smem + bsel_ * 16384;                                    \
    const bf16* bB_ = bA_ + 8192;                                              \
    bf16* sA_ = smem + (((T_) + 3) & 3) * 16384;                               \
    bf16* sB_ = sA_ + 8192;                                                    \
    const int ko_ = ((T_) + 3) * 32;                                           \
    bf16x8 afr_[4], bfg_[4];                                                   \
    _Pragma("unroll")                                                          \
    for (int mf = 0; mf < 4; mf++) afr_[mf] = *(const bf16x8*)(bA_ + aoff[mf]);\
    _Pragma("unroll")                                                          \
    for (int nf = 0; nf < 4; nf++) bfg_[nf] = *(const bf16x8*)(bB_ + boff[nf]);\
    if (DO_STAGE_) {                                                           \
        load_lds16(gA0 + ko_, sA_ + soff0);                                    \
        load_lds16(gA1 + ko_, sA_ + soff1);                                    \
    }                                                                          \
    __builtin_amdgcn_s_barrier();                                              \
    __builtin_amdgcn_s_setprio(1);                                             \
    _Pragma("unroll")                                                          \
    for (int mf = 0; mf < 4; mf++)                                             \
        _Pragma("unroll")                                                      \
        for (int nf = 0; nf < 4; nf++)                                         \
            acc[mf][nf] = __builtin_amdgcn_mfma_f32_16x16x32_bf16(             \
                afr_[mf], bfg_[nf], acc[mf][nf], 0, 0, 0);                     \
    __builtin_amdgcn_s_setprio(0);                                             \
    __builtin_amdgcn_s_barrier();                                              \
    _Pragma("unroll")                                                          \
    for (int mf = 0; mf < 4; mf++)                                             \
        afr_[mf] = *(const bf16x8*)(bA_ + aoff[4 + mf]);                       \
    if (DO_STAGE_) {                                                           \
        load_lds16(gB0 + ko_, sB_ + soff0);                                    \
        load_lds16(gB1 + ko_, sB_ + soff1);                                    \
    }                                                                          \
    __builtin_amdgcn_s_barrier();                                              \
    __builtin_amdgcn_s_setprio(1);                                             \
    _Pragma("unroll")                                                          \
    for (int mf = 0; mf < 4; mf++)                                             \
        _Pragma("unroll")                                                      \
        for (int nf = 0; nf < 4; nf++)                                         \
            acc[4 + mf][nf] = __builtin_amdgcn_mfma_f32_16x16x32_bf16(         \
                afr_[mf], bfg_[nf], acc[4 + mf][nf], 0, 0, 0);                 \
    __builtin_amdgcn_s_setprio(0);                                             \
    asm volatile(WAITSTR_ ::: "memory");                                       \
    __builtin_amdgcn_s_barrier();                                              \
} while (0)

__global__ __launch_bounds__(512, 2) void gemm_qkv(const bf16* __restrict__ A,
                                                   const bf16* __restrict__ W,
                                                   const float* __restrict__ bq,
                                                   const float* __restrict__ bk,
                                                   const float* __restrict__ bv,
                                                   bf16* __restrict__ Qo,
                                                   bf16* __restrict__ Ko,
                                                   bf16* __restrict__ Vt) {
    __shared__ __align__(16) bf16 smem[4 * 16384];   // 128 KiB

    const int tid  = threadIdx.x;
    const int wave = tid >> 6, lane = tid & 63;
    const int quad = lane >> 4, l16 = lane & 15;
    const int wr = wave >> 2, wc = wave & 3;         // 2 x 4 wave grid

    // bijective XCD swizzle: 384 = 8 * 48
    const int wg = (blockIdx.x & 7) * 48 + (blockIdx.x >> 3);
    const int mt = wg / 12, inner = wg % 12;
    const int sel = inner >> 2, nt = inner & 3;      // 0=Q 1=K 2=V
    const int m0 = mt * 256, n0 = nt * 256;

    const bf16* Wsel = W + (size_t)(sel * DIM + n0) * DIM;
    const float* bias = (sel == 0) ? bq : (sel == 1) ? bk : bv;

    // ds_read fragment offsets (elements), T2-swizzled
    int aoff[8], boff[4];
#pragma unroll
    for (int mf = 0; mf < 8; mf++) {
        const int row = wr * 128 + mf * 16 + l16;
        aoff[mf] = row * 32 + ((quad ^ ((row >> 1) & 3)) * 8);
    }
#pragma unroll
    for (int nf = 0; nf < 4; nf++) {
        const int row = wc * 64 + nf * 16 + l16;
        boff[nf] = row * 32 + ((quad ^ ((row >> 1) & 3)) * 8);
    }

    // staging: per K-tile, A = 1024 chunks of 16B (2/thread), B likewise.
    // chunk c -> LDS linear c*16B; source row = c>>2, k-slot (c&3)^((row>>1)&3)
    const int c0 = tid, c1 = tid + 512;
    const int ra0 = c0 >> 2, qa0 = (c0 & 3) ^ ((ra0 >> 1) & 3);
    const int ra1 = c1 >> 2, qa1 = (c1 & 3) ^ ((ra1 >> 1) & 3);
    const bf16* gA0 = A + (size_t)(m0 + ra0) * DIM + qa0 * 8;
    const bf16* gA1 = A + (size_t)(m0 + ra1) * DIM + qa1 * 8;
    const bf16* gB0 = Wsel + (size_t)ra0 * DIM + qa0 * 8;
    const bf16* gB1 = Wsel + (size_t)ra1 * DIM + qa1 * 8;
    const int soff0 = (wave * 64) * 8;               // wave-uniform LDS bases
    const int soff1 = (512 + wave * 64) * 8;

    floatx4 acc[8][4];
#pragma unroll
    for (int mf = 0; mf < 8; mf++)
#pragma unroll
        for (int nf = 0; nf < 4; nf++) acc[mf][nf] = zero4();

    // prologue: stage K-tiles 0,1,2 into buffers 0,1,2
#pragma unroll
    for (int kt = 0; kt < 3; kt++) {
        bf16* sA = smem + kt * 16384;
        bf16* sB = sA + 8192;
        load_lds16(gA0 + kt * 32, sA + soff0);
        load_lds16(gA1 + kt * 32, sA + soff1);
        load_lds16(gB0 + kt * 32, sB + soff0);
        load_lds16(gB1 + kt * 32, sB + soff1);
    }
    asm volatile("s_waitcnt vmcnt(8)" ::: "memory");   // tile 0 landed
    __builtin_amdgcn_s_barrier();

    const int NT = DIM / 32;   // 32 K-tiles
#pragma unroll 1
    for (int t = 0; t < NT - 3; t++)
        QKV_TILE(t, true, "s_waitcnt vmcnt(8)");
    QKV_TILE(NT - 3, false, "s_waitcnt vmcnt(4)");
    QKV_TILE(NT - 2, false, "s_waitcnt vmcnt(0)");
    QKV_TILE(NT - 1, false, "s_waitcnt vmcnt(0)");

    if (sel < 2) {
        bf16* C = (sel == 0) ? Qo : Ko;
        const float scale = (sel == 0) ? CEXP : 1.0f;
#pragma unroll
        for (int mf = 0; mf < 8; mf++) {
            const int rbase = m0 + wr * 128 + mf * 16 + quad * 4;
#pragma unroll
            for (int nf = 0; nf < 4; nf++) {
                const int col = n0 + wc * 64 + nf * 16 + l16;
                const float bval = bias[col];
#pragma unroll
                for (int i = 0; i < 4; i++)
                    C[(size_t)(rbase + i) * DIM + col] =
                        (bf16)((acc[mf][nf][i] + bval) * scale);
            }
        }
    } else {
        // V: transpose 256x256 tile via 128KB LDS -> Vt[(b*NH+h)][d][s]
        // LDS elem(n, m) = n*256 + (((m*2) ^ ((n&7)<<4)) >> 1)
        const int b  = m0 >> 11;           // m0 / SEQ
        const int s0 = m0 & (SEQ - 1);
#pragma unroll
        for (int mf = 0; mf < 8; mf++) {
            const int mb = wr * 128 + mf * 16 + quad * 4;
#pragma unroll
            for (int nf = 0; nf < 4; nf++) {
                const int n_loc = wc * 64 + nf * 16 + l16;
                const float bval = bias[n0 + n_loc];
                bf16x4 pk;
#pragma unroll
                for (int i = 0; i < 4; i++) pk[i] = (bf16)(acc[mf][nf][i] + bval);
                const int e = n_loc * 256 + (((mb * 2) ^ ((n_loc & 7) << 4)) >> 1);
                *(bf16x4*)(smem + e) = pk;
            }
        }
        asm volatile("s_waitcnt lgkmcnt(0)" ::: "memory");
        __builtin_amdgcn_s_barrier();
#pragma unroll
        for (int p = 0; p < 16; p++) {
            const int c = p * 512 + tid;
            const int n_loc = c >> 5, mc = (c & 31) * 8;
            const int e = n_loc * 256 + (((mc * 2) ^ ((n_loc & 7) << 4)) >> 1);
            bf16x8 v = *(const bf16x8*)(smem + e);
            const int dg = n0 + n_loc;
            const int hh = dg >> 6, d = dg & 63;
            bf16* op = Vt + ((size_t)(b * NH + hh) * DH + d) * SEQ + s0 + mc;
            *(bf16x8*)op = v;
        }
    }
}

// ---------------------------------------------------------------------------
// Out-projection GEMM (fp32 out), 128x128 tiles.
// ---------------------------------------------------------------------------
__global__ __launch_bounds__(256) void gemm_out(const bf16* __restrict__ A,
                                                const bf16* __restrict__ W,
                                                const float* __restrict__ bias,
                                                float* __restrict__ C) {
    __shared__ __align__(16) bf16 As[128 * 32];
    __shared__ __align__(16) bf16 Bs[128 * 32];

    const int tid  = threadIdx.x;
    const int wave = tid >> 6, lane = tid & 63;
    const int quad = lane >> 4, l16 = lane & 15;
    const int m0 = blockIdx.y * 128, n0 = blockIdx.x * 128;
    const int wm = (wave & 1) * 64, wn = (wave >> 1) * 64;

    floatx4 acc[4][4];
#pragma unroll
    for (int mi = 0; mi < 4; mi++)
#pragma unroll
        for (int ni = 0; ni < 4; ni++) acc[mi][ni] = zero4();

    for (int k0 = 0; k0 < DIM; k0 += 32) {
        __syncthreads();
#pragma unroll
        for (int i = 0; i < 2; i++) {
            const int cb = wave * 128 + i * 64;
            const int c  = cb + lane;
            const int row = c >> 2;
            const int kc  = (c & 3) * 8;
            load_lds16(A + (size_t)(m0 + row) * DIM + k0 + kc, &As[cb * 8]);
            load_lds16(W + (size_t)(n0 + row) * DIM + k0 + kc, &Bs[cb * 8]);
        }
        __syncthreads();

        bf16x8 af[4], bfr[4];
#pragma unroll
        for (int mi = 0; mi < 4; mi++)
            af[mi] = *(const bf16x8*)&As[(wm + mi * 16 + l16) * 32 + quad * 8];
#pragma unroll
        for (int ni = 0; ni < 4; ni++)
            bfr[ni] = *(const bf16x8*)&Bs[(wn + ni * 16 + l16) * 32 + quad * 8];
#pragma unroll
        for (int mi = 0; mi < 4; mi++)
#pragma unroll
            for (int ni = 0; ni < 4; ni++)
                acc[mi][ni] = __builtin_amdgcn_mfma_f32_16x16x32_bf16(
                    af[mi], bfr[ni], acc[mi][ni], 0, 0, 0);
    }

#pragma unroll
    for (int mi = 0; mi < 4; mi++) {
        const int rbase = m0 + wm + mi * 16 + quad * 4;
#pragma unroll
        for (int ni = 0; ni < 4; ni++) {
            const int col = n0 + wn + ni * 16 + l16;
            const float bval = bias[col];
#pragma unroll
            for (int i = 0; i < 4; i++)
                C[(size_t)(rbase + i) * DIM + col] = acc[mi][ni][i] + bval;
        }
    }
}

// ---------------------------------------------------------------------------
// Flash attention: 4-wave blocks = 128 q rows of one (b,h), 32 q/wave.
// XCD-swizzled grid (L2-resident K/V). K rows staged PERMUTED within each
// 32-kv window so PV runs at K=32; V staged in natural [d][s] order.
// Q pre-scaled by CEXP -> P = exp2(z). (unchanged)
// ---------------------------------------------------------------------------
__global__ __launch_bounds__(256, 4) void attn_kernel(const bf16* __restrict__ Q,
                                                      const bf16* __restrict__ K,
                                                      const bf16* __restrict__ Vt,
                                                      bf16* __restrict__ Ctx) {
    __shared__ __align__(16) bf16 Ks[2][64 * 64];  // swizzled, kv-permuted
    __shared__ __align__(16) bf16 Vs[2][64 * 64];  // swizzled, natural order

    const int tid  = threadIdx.x;
    const int wave = tid >> 6, lane = tid & 63;
    const int quad = lane >> 4, l16 = lane & 15;
    // XCD-aware swizzle (1024 blocks, 8 XCDs)
    const int xcd = blockIdx.x & 7;
    const int j   = blockIdx.x >> 3;        // 0..127
    const int bh  = xcd * 8 + (j >> 4);     // b*NH + h
    const int qb  = j & 15;                 // 128-row q block
    const int b   = bh >> 4, h = bh & 15;

    const size_t base_bh = (size_t)b * SEQ * DIM + (size_t)h * DH;
    const size_t base_v  = (size_t)bh * DH * SEQ;
    const int qt = qb * 128 + wave * 32;    // wave's 32 q rows

    // Q frags (B-operand of swapped QK MFMA): 2 m-subtiles x 2 d-halves
    bf16x8 aq[2][2];
#pragma unroll
    for (int m = 0; m < 2; m++) {
        const bf16* qp = Q + base_bh + (size_t)(qt + m * 16 + l16) * DIM + quad * 8;
        aq[m][0] = *(const bf16x8*)qp;
        aq[m][1] = *(const bf16x8*)(qp + 32);
    }

    // staging addresses (kv-invariant): chunk ids sc, sc+64 per array
    const int sc = wave * 128 + lane;
    int srow[2], scol[2];
    srow[0] = sc >> 3;        srow[1] = (sc + 64) >> 3;
    scol[0] = (sc & 7) ^ (srow[0] & 7);
    scol[1] = ((sc + 64) & 7) ^ (srow[1] & 7);
    // K permuted kv offset for a physical row r
    auto kvloc = [](int r) {
        const int w = r >> 5, rw = r & 31, r4 = rw & 15;
        return w * 32 + ((rw >> 4) << 2) + ((r4 >> 2) << 3) + (r4 & 3);
    };
    const bf16* kga = K + base_bh + (size_t)kvloc(srow[0]) * DIM + scol[0] * 8;
    const bf16* kgb = K + base_bh + (size_t)kvloc(srow[1]) * DIM + scol[1] * 8;
    const bf16* vga = Vt + base_v + (size_t)srow[0] * SEQ + scol[0] * 8;
    const bf16* vgb = Vt + base_v + (size_t)srow[1] * SEQ + scol[1] * 8;
    const int ldsa = (wave * 128) * 8, ldsb = (wave * 128 + 64) * 8;

    // LDS read offsets (kv-invariant): K frags per group g, V per (w,dt)
    int koa[4], kob[4], vo[2][4];
#pragma unroll
    for (int g = 0; g < 4; g++) {
        const int krow = g * 16 + l16;
        koa[g] = (krow * 8 + (quad ^ (krow & 7))) * 8;
        kob[g] = (krow * 8 + ((4 + quad) ^ (krow & 7))) * 8;
    }
#pragma unroll
    for (int w = 0; w < 2; w++)
#pragma unroll
        for (int dt = 0; dt < 4; dt++) {
            const int d = dt * 16 + l16;
            vo[w][dt] = d * 64 + ((4 * w + quad) ^ (d & 7)) * 8;
        }

    bf16x8 ones8;
#pragma unroll
    for (int i = 0; i < 8; i++) ones8[i] = (bf16)1.0f;

    floatx4 acc[2][4], accl[2];
#pragma unroll
    for (int m = 0; m < 2; m++) {
        accl[m] = zero4();
#pragma unroll
        for (int dt = 0; dt < 4; dt++) acc[m][dt] = zero4();
    }

    // prologue: stage tile 0 into buffer 0
    load_lds16(kga, &Ks[0][ldsa]);
    load_lds16(kgb, &Ks[0][ldsb]);
    load_lds16(vga, &Vs[0][ldsa]);
    load_lds16(vgb, &Vs[0][ldsb]);

    for (int it = 0; it < SEQ / 64; it++) {
        __syncthreads();  // drains staging issued last iter; readers done
        const int cur = it & 1;
        if (it + 1 < SEQ / 64) {
            const int nxt = cur ^ 1;
            const size_t kvn = (size_t)(it + 1) * 64;
            load_lds16(kga + kvn * DIM, &Ks[nxt][ldsa]);
            load_lds16(kgb + kvn * DIM, &Ks[nxt][ldsb]);
            load_lds16(vga + kvn, &Vs[nxt][ldsa]);
            load_lds16(vgb + kvn, &Vs[nxt][ldsb]);
        }

#pragma unroll
        for (int w = 0; w < 2; w++) {
            // K frags for groups 2w (even: k=8q..8q+3), 2w+1 (odd: 8q+4..7)
            const bf16x8 ke0 = *(const bf16x8*)&Ks[cur][koa[2 * w]];
            const bf16x8 ke1 = *(const bf16x8*)&Ks[cur][kob[2 * w]];
            const bf16x8 ko0 = *(const bf16x8*)&Ks[cur][koa[2 * w + 1]];
            const bf16x8 ko1 = *(const bf16x8*)&Ks[cur][kob[2 * w + 1]];
            bf16x8 pw[2];
#pragma unroll
            for (int m = 0; m < 2; m++) {
                floatx4 sa = zero4(), sb = zero4();
                sa = __builtin_amdgcn_mfma_f32_16x16x32_bf16(ke0, aq[m][0], sa, 0, 0, 0);
                sa = __builtin_amdgcn_mfma_f32_16x16x32_bf16(ke1, aq[m][1], sa, 0, 0, 0);
                sb = __builtin_amdgcn_mfma_f32_16x16x32_bf16(ko0, aq[m][0], sb, 0, 0, 0);
                sb = __builtin_amdgcn_mfma_f32_16x16x32_bf16(ko1, aq[m][1], sb, 0, 0, 0);
                bf16x8 p;
#pragma unroll
                for (int i = 0; i < 4; i++) {
                    p[i]     = (bf16)__builtin_amdgcn_exp2f(sa[i]);
                    p[4 + i] = (bf16)__builtin_amdgcn_exp2f(sb[i]);
                }
                pw[m] = p;
            }
            // V frags: b128, natural kv order
            bf16x8 vf[4];
#pragma unroll
            for (int dt = 0; dt < 4; dt++)
                vf[dt] = *(const bf16x8*)&Vs[cur][vo[w][dt]];
#pragma unroll
            for (int m = 0; m < 2; m++) {
#pragma unroll
                for (int dt = 0; dt < 4; dt++)
                    acc[m][dt] = __builtin_amdgcn_mfma_f32_16x16x32_bf16(
                        pw[m], vf[dt], acc[m][dt], 0, 0, 0);
                accl[m] = __builtin_amdgcn_mfma_f32_16x16x32_bf16(
                    pw[m], ones8, accl[m], 0, 0, 0);
            }
        }
    }

    // store: O rows q=qt+m*16+quad*4+i, cols dt*16+l16
#pragma unroll
    for (int m = 0; m < 2; m++) {
        float inv[4];
#pragma unroll
        for (int i = 0; i < 4; i++) inv[i] = 1.0f / accl[m][i];
        bf16* cp = Ctx + base_bh + (size_t)(qt + m * 16 + quad * 4) * DIM + l16;
#pragma unroll
        for (int i = 0; i < 4; i++)
#pragma unroll
            for (int dt = 0; dt < 4; dt++)
                cp[(size_t)i * DIM + dt * 16] = (bf16)(acc[m][dt][i] * inv[i]);
    }
}

// ---------------------------------------------------------------------------
extern "C" void kernel_launch(void* const* d_in, const int* in_sizes, int n_in,
                              void* d_out, int out_size, void* d_ws, size_t ws_size,
                              hipStream_t stream) {
    const float* X  = (const float*)d_in[0];
    const float* Wq = (const float*)d_in[1];
    const float* bq = (const float*)d_in[2];
    const float* Wk = (const float*)d_in[3];
    const float* bk = (const float*)d_in[4];
    const float* Wv = (const float*)d_in[5];
    const float* bv = (const float*)d_in[6];
    const float* Wo = (const float*)d_in[7];
    const float* bo = (const float*)d_in[8];
    float* out = (float*)d_out;

    const size_t MD = (size_t)MTOT * DIM;
    const size_t DD = (size_t)DIM * DIM;

    bf16* Xb  = (bf16*)d_ws;     // X bf16; reused as ctx after attention
    bf16* Qb  = Xb + MD;
    bf16* Kb  = Qb + MD;
    bf16* Vtb = Kb + MD;         // V transposed [B*H][DH][SEQ]
    bf16* Wqb = Vtb + MD;        // [Wq;Wk;Wv;Wo] rows contiguous
    bf16* Wob = Wqb + 3 * DD;
    if (ws_size < (MD * 4 + DD * 4) * sizeof(bf16)) return;

    cvt_all<<<(int)((MD + 4 * DD) / 4 / 256), 256, 0, stream>>>(
        X, Wq, Wk, Wv, Wo, Xb, Wqb);

    // 384 blocks x 512 threads: 32 m-tiles x {Q,K,V} x 4 n-tiles
    gemm_qkv<<<384, 512, 0, stream>>>(Xb, Wqb, bq, bk, bv, Qb, Kb, Vtb);

    // 1024 blocks x 256 threads: XCD-swizzled 64 (b,h) x 16 q-blocks
    attn_kernel<<<NB * NH * (SEQ / 128), 256, 0, stream>>>(Qb, Kb, Vtb, Xb);

    gemm_out<<<dim3(8, MTOT / 128), 256, 0, stream>>>(Xb, Wob, bo, out);
}

// Round 3
// 260.636 us; speedup vs baseline: 1.0778x; 1.0421x over previous
//
#include <hip/hip_runtime.h>

// ---------------------------------------------------------------------------
// AttentionActPrune — full MHA forward. B=4, S=2048, H=16, DH=64, D=1024.
// fp32 in/out; threshold 2% of max|ref| -> bf16 MFMA compute.
// Pipeline: cvt_all -> merged QKV GEMM (256x256 tile, BK=32, 4-buffer 128KB
// LDS, counted-vmcnt deep pipeline, NOW 1 barrier/K-tile) -> flash-attn
// (NOW 64 q-rows/wave: 2x MFMA per LDS read) -> GEMM out (128x128).
// ---------------------------------------------------------------------------

typedef __bf16 bf16;
typedef __bf16 bf16x8 __attribute__((ext_vector_type(8)));
typedef __bf16 bf16x4 __attribute__((ext_vector_type(4)));
typedef float  floatx4 __attribute__((ext_vector_type(4)));

#define NB   4
#define SEQ  2048
#define NH   16
#define DH   64
#define DIM  1024
#define MTOT (NB * SEQ)   // 8192

#define CEXP 0.18033688f   // (1/sqrt(DH)) * log2(e), folded into Q

__device__ __forceinline__ floatx4 zero4() {
    floatx4 z; z[0] = 0.f; z[1] = 0.f; z[2] = 0.f; z[3] = 0.f; return z;
}

__device__ __forceinline__ void load_lds16(const bf16* g, bf16* l) {
    __builtin_amdgcn_global_load_lds(
        (__attribute__((address_space(1))) void*)g,
        (__attribute__((address_space(3))) void*)l,
        16, 0, 0);
}

// ---------------------------------------------------------------------------
// fp32 -> bf16 converts: X (MD elems) then [Wq;Wk;Wv;Wo] (4*DD) in one grid.
// ---------------------------------------------------------------------------
__global__ __launch_bounds__(256) void cvt_all(const float* __restrict__ X,
                                               const float* __restrict__ w0,
                                               const float* __restrict__ w1,
                                               const float* __restrict__ w2,
                                               const float* __restrict__ w3,
                                               bf16* __restrict__ Xb,
                                               bf16* __restrict__ Wb) {
    const size_t MD = (size_t)MTOT * DIM;
    const size_t DD = (size_t)DIM * DIM;   // 2^20
    size_t i = ((size_t)blockIdx.x * 256 + threadIdx.x) * 4;
    float4 f; bf16* dst;
    if (i < MD) {
        f = *(const float4*)(X + i);
        dst = Xb + i;
    } else {
        size_t off = i - MD;
        int w = (int)(off >> 20);
        size_t wi = off & (DD - 1);
        const float* ws = (w == 0) ? w0 : (w == 1) ? w1 : (w == 2) ? w2 : w3;
        f = *(const float4*)(ws + wi);
        dst = Wb + off;
    }
    bf16x4 o;
    o[0] = (bf16)f.x; o[1] = (bf16)f.y; o[2] = (bf16)f.z; o[3] = (bf16)f.w;
    *(bf16x4*)dst = o;
}

// ---------------------------------------------------------------------------
// Merged QKV GEMM, 256x256 tiles, deep-pipelined, 1 barrier per K-tile.
//   Per K-tile: {stage x4 -> buf[t+3]; ds_read A0-3,B0-3; MFMA x16;
//   ds_read A4-7; MFMA x16; vmcnt(8); barrier}.
//   Hazards: stage(t) targets buf[(t-1)&3] whose readers' ds_reads were
//   consumed by MFMAs before the end-of-(t-1) barrier; per-wave vmcnt(8)
//   before the shared barrier => tile t+1 fully staged for all waves.
// ---------------------------------------------------------------------------
#define QKV_TILE(T_, DO_STAGE_, WAITSTR_) do {                                 \
    const bf16* bA_ = smem + ((T_) & 3) * 16384;                               \
    const bf16* bB_ = bA_ + 8192;                                              \
    if (DO_STAGE_) {                                                           \
        bf16* sA_ = smem + (((T_) + 3) & 3) * 16384;                           \
        const int ko_ = ((T_) + 3) * 32;                                       \
        load_lds16(gA0 + ko_, sA_ + soff0);                                    \
        load_lds16(gA1 + ko_, sA_ + soff1);                                    \
        load_lds16(gB0 + ko_, sA_ + 8192 + soff0);                             \
        load_lds16(gB1 + ko_, sA_ + 8192 + soff1);                             \
    }                                                                          \
    bf16x8 afr_[4], bfg_[4];                                                   \
    _Pragma("unroll")                                                          \
    for (int mf = 0; mf < 4; mf++) afr_[mf] = *(const bf16x8*)(bA_ + aoff[mf]);\
    _Pragma("unroll")                                                          \
    for (int nf = 0; nf < 4; nf++) bfg_[nf] = *(const bf16x8*)(bB_ + boff[nf]);\
    __builtin_amdgcn_s_setprio(1);                                             \
    _Pragma("unroll")                                                          \
    for (int mf = 0; mf < 4; mf++)                                             \
        _Pragma("unroll")                                                      \
        for (int nf = 0; nf < 4; nf++)                                         \
            acc[mf][nf] = __builtin_amdgcn_mfma_f32_16x16x32_bf16(             \
                afr_[mf], bfg_[nf], acc[mf][nf], 0, 0, 0);                     \
    __builtin_amdgcn_s_setprio(0);                                             \
    _Pragma("unroll")                                                          \
    for (int mf = 0; mf < 4; mf++)                                             \
        afr_[mf] = *(const bf16x8*)(bA_ + aoff[4 + mf]);                       \
    __builtin_amdgcn_s_setprio(1);                                             \
    _Pragma("unroll")                                                          \
    for (int mf = 0; mf < 4; mf++)                                             \
        _Pragma("unroll")                                                      \
        for (int nf = 0; nf < 4; nf++)                                         \
            acc[4 + mf][nf] = __builtin_amdgcn_mfma_f32_16x16x32_bf16(         \
                afr_[mf], bfg_[nf], acc[4 + mf][nf], 0, 0, 0);                 \
    __builtin_amdgcn_s_setprio(0);                                             \
    asm volatile(WAITSTR_ ::: "memory");                                       \
    __builtin_amdgcn_s_barrier();                                              \
} while (0)

__global__ __launch_bounds__(512, 2) void gemm_qkv(const bf16* __restrict__ A,
                                                   const bf16* __restrict__ W,
                                                   const float* __restrict__ bq,
                                                   const float* __restrict__ bk,
                                                   const float* __restrict__ bv,
                                                   bf16* __restrict__ Qo,
                                                   bf16* __restrict__ Ko,
                                                   bf16* __restrict__ Vt) {
    __shared__ __align__(16) bf16 smem[4 * 16384];   // 128 KiB

    const int tid  = threadIdx.x;
    const int wave = tid >> 6, lane = tid & 63;
    const int quad = lane >> 4, l16 = lane & 15;
    const int wr = wave >> 2, wc = wave & 3;         // 2 x 4 wave grid

    // bijective XCD swizzle: 384 = 8 * 48
    const int wg = (blockIdx.x & 7) * 48 + (blockIdx.x >> 3);
    const int mt = wg / 12, inner = wg % 12;
    const int sel = inner >> 2, nt = inner & 3;      // 0=Q 1=K 2=V
    const int m0 = mt * 256, n0 = nt * 256;

    const bf16* Wsel = W + (size_t)(sel * DIM + n0) * DIM;
    const float* bias = (sel == 0) ? bq : (sel == 1) ? bk : bv;

    // ds_read fragment offsets (elements), T2-swizzled
    int aoff[8], boff[4];
#pragma unroll
    for (int mf = 0; mf < 8; mf++) {
        const int row = wr * 128 + mf * 16 + l16;
        aoff[mf] = row * 32 + ((quad ^ ((row >> 1) & 3)) * 8);
    }
#pragma unroll
    for (int nf = 0; nf < 4; nf++) {
        const int row = wc * 64 + nf * 16 + l16;
        boff[nf] = row * 32 + ((quad ^ ((row >> 1) & 3)) * 8);
    }

    // staging: per K-tile, A = 1024 chunks of 16B (2/thread), B likewise.
    // chunk c -> LDS linear c*16B; source row = c>>2, k-slot (c&3)^((row>>1)&3)
    const int c0 = tid, c1 = tid + 512;
    const int ra0 = c0 >> 2, qa0 = (c0 & 3) ^ ((ra0 >> 1) & 3);
    const int ra1 = c1 >> 2, qa1 = (c1 & 3) ^ ((ra1 >> 1) & 3);
    const bf16* gA0 = A + (size_t)(m0 + ra0) * DIM + qa0 * 8;
    const bf16* gA1 = A + (size_t)(m0 + ra1) * DIM + qa1 * 8;
    const bf16* gB0 = Wsel + (size_t)ra0 * DIM + qa0 * 8;
    const bf16* gB1 = Wsel + (size_t)ra1 * DIM + qa1 * 8;
    const int soff0 = (wave * 64) * 8;               // wave-uniform LDS bases
    const int soff1 = (512 + wave * 64) * 8;

    floatx4 acc[8][4];
#pragma unroll
    for (int mf = 0; mf < 8; mf++)
#pragma unroll
        for (int nf = 0; nf < 4; nf++) acc[mf][nf] = zero4();

    // prologue: stage K-tiles 0,1,2 into buffers 0,1,2
#pragma unroll
    for (int kt = 0; kt < 3; kt++) {
        bf16* sA = smem + kt * 16384;
        bf16* sB = sA + 8192;
        load_lds16(gA0 + kt * 32, sA + soff0);
        load_lds16(gA1 + kt * 32, sA + soff1);
        load_lds16(gB0 + kt * 32, sB + soff0);
        load_lds16(gB1 + kt * 32, sB + soff1);
    }
    asm volatile("s_waitcnt vmcnt(8)" ::: "memory");   // tile 0 landed
    __builtin_amdgcn_s_barrier();

    const int NT = DIM / 32;   // 32 K-tiles
#pragma unroll 1
    for (int t = 0; t < NT - 3; t++)
        QKV_TILE(t, true, "s_waitcnt vmcnt(8)");
    QKV_TILE(NT - 3, false, "s_waitcnt vmcnt(4)");
    QKV_TILE(NT - 2, false, "s_waitcnt vmcnt(0)");
    QKV_TILE(NT - 1, false, "s_waitcnt vmcnt(0)");

    if (sel < 2) {
        bf16* C = (sel == 0) ? Qo : Ko;
        const float scale = (sel == 0) ? CEXP : 1.0f;
#pragma unroll
        for (int mf = 0; mf < 8; mf++) {
            const int rbase = m0 + wr * 128 + mf * 16 + quad * 4;
#pragma unroll
            for (int nf = 0; nf < 4; nf++) {
                const int col = n0 + wc * 64 + nf * 16 + l16;
                const float bval = bias[col];
#pragma unroll
                for (int i = 0; i < 4; i++)
                    C[(size_t)(rbase + i) * DIM + col] =
                        (bf16)((acc[mf][nf][i] + bval) * scale);
            }
        }
    } else {
        // V: transpose 256x256 tile via 128KB LDS -> Vt[(b*NH+h)][d][s]
        // LDS elem(n, m) = n*256 + (((m*2) ^ ((n&7)<<4)) >> 1)
        const int b  = m0 >> 11;           // m0 / SEQ
        const int s0 = m0 & (SEQ - 1);
#pragma unroll
        for (int mf = 0; mf < 8; mf++) {
            const int mb = wr * 128 + mf * 16 + quad * 4;
#pragma unroll
            for (int nf = 0; nf < 4; nf++) {
                const int n_loc = wc * 64 + nf * 16 + l16;
                const float bval = bias[n0 + n_loc];
                bf16x4 pk;
#pragma unroll
                for (int i = 0; i < 4; i++) pk[i] = (bf16)(acc[mf][nf][i] + bval);
                const int e = n_loc * 256 + (((mb * 2) ^ ((n_loc & 7) << 4)) >> 1);
                *(bf16x4*)(smem + e) = pk;
            }
        }
        asm volatile("s_waitcnt lgkmcnt(0)" ::: "memory");
        __builtin_amdgcn_s_barrier();
#pragma unroll
        for (int p = 0; p < 16; p++) {
            const int c = p * 512 + tid;
            const int n_loc = c >> 5, mc = (c & 31) * 8;
            const int e = n_loc * 256 + (((mc * 2) ^ ((n_loc & 7) << 4)) >> 1);
            bf16x8 v = *(const bf16x8*)(smem + e);
            const int dg = n0 + n_loc;
            const int hh = dg >> 6, d = dg & 63;
            bf16* op = Vt + ((size_t)(b * NH + hh) * DH + d) * SEQ + s0 + mc;
            *(bf16x8*)op = v;
        }
    }
}

// ---------------------------------------------------------------------------
// Out-projection GEMM (fp32 out), 128x128 tiles.
// ---------------------------------------------------------------------------
__global__ __launch_bounds__(256) void gemm_out(const bf16* __restrict__ A,
                                                const bf16* __restrict__ W,
                                                const float* __restrict__ bias,
                                                float* __restrict__ C) {
    __shared__ __align__(16) bf16 As[128 * 32];
    __shared__ __align__(16) bf16 Bs[128 * 32];

    const int tid  = threadIdx.x;
    const int wave = tid >> 6, lane = tid & 63;
    const int quad = lane >> 4, l16 = lane & 15;
    const int m0 = blockIdx.y * 128, n0 = blockIdx.x * 128;
    const int wm = (wave & 1) * 64, wn = (wave >> 1) * 64;

    floatx4 acc[4][4];
#pragma unroll
    for (int mi = 0; mi < 4; mi++)
#pragma unroll
        for (int ni = 0; ni < 4; ni++) acc[mi][ni] = zero4();

    for (int k0 = 0; k0 < DIM; k0 += 32) {
        __syncthreads();
#pragma unroll
        for (int i = 0; i < 2; i++) {
            const int cb = wave * 128 + i * 64;
            const int c  = cb + lane;
            const int row = c >> 2;
            const int kc  = (c & 3) * 8;
            load_lds16(A + (size_t)(m0 + row) * DIM + k0 + kc, &As[cb * 8]);
            load_lds16(W + (size_t)(n0 + row) * DIM + k0 + kc, &Bs[cb * 8]);
        }
        __syncthreads();

        bf16x8 af[4], bfr[4];
#pragma unroll
        for (int mi = 0; mi < 4; mi++)
            af[mi] = *(const bf16x8*)&As[(wm + mi * 16 + l16) * 32 + quad * 8];
#pragma unroll
        for (int ni = 0; ni < 4; ni++)
            bfr[ni] = *(const bf16x8*)&Bs[(wn + ni * 16 + l16) * 32 + quad * 8];
#pragma unroll
        for (int mi = 0; mi < 4; mi++)
#pragma unroll
            for (int ni = 0; ni < 4; ni++)
                acc[mi][ni] = __builtin_amdgcn_mfma_f32_16x16x32_bf16(
                    af[mi], bfr[ni], acc[mi][ni], 0, 0, 0);
    }

#pragma unroll
    for (int mi = 0; mi < 4; mi++) {
        const int rbase = m0 + wm + mi * 16 + quad * 4;
#pragma unroll
        for (int ni = 0; ni < 4; ni++) {
            const int col = n0 + wn + ni * 16 + l16;
            const float bval = bias[col];
#pragma unroll
            for (int i = 0; i < 4; i++)
                C[(size_t)(rbase + i) * DIM + col] = acc[mi][ni][i] + bval;
        }
    }
}

// ---------------------------------------------------------------------------
// Flash attention: 4-wave blocks = 256 q rows of one (b,h), 64 q/wave.
// (2x MFMA per LDS-read/K-frag vs round-2's 32 q/wave.)
// XCD-swizzled grid (L2-resident K/V). K rows staged PERMUTED within each
// 32-kv window so PV runs at K=32; V staged in natural [d][s] order.
// Q pre-scaled by CEXP -> P = exp2(z).
// ---------------------------------------------------------------------------
__global__ __launch_bounds__(256, 2) void attn_kernel(const bf16* __restrict__ Q,
                                                      const bf16* __restrict__ K,
                                                      const bf16* __restrict__ Vt,
                                                      bf16* __restrict__ Ctx) {
    __shared__ __align__(16) bf16 Ks[2][64 * 64];  // swizzled, kv-permuted
    __shared__ __align__(16) bf16 Vs[2][64 * 64];  // swizzled, natural order

    const int tid  = threadIdx.x;
    const int wave = tid >> 6, lane = tid & 63;
    const int quad = lane >> 4, l16 = lane & 15;
    // XCD-aware swizzle (512 blocks, 8 XCDs): 8 bh per XCD
    const int xcd = blockIdx.x & 7;
    const int j   = blockIdx.x >> 3;        // 0..63
    const int bh  = xcd * 8 + (j >> 3);     // b*NH + h
    const int qb  = j & 7;                  // 256-row q block
    const int b   = bh >> 4, h = bh & 15;

    const size_t base_bh = (size_t)b * SEQ * DIM + (size_t)h * DH;
    const size_t base_v  = (size_t)bh * DH * SEQ;
    const int qt = qb * 256 + wave * 64;    // wave's 64 q rows

    // Q frags (B-operand of swapped QK MFMA): 4 m-subtiles x 2 d-halves
    bf16x8 aq[4][2];
#pragma unroll
    for (int m = 0; m < 4; m++) {
        const bf16* qp = Q + base_bh + (size_t)(qt + m * 16 + l16) * DIM + quad * 8;
        aq[m][0] = *(const bf16x8*)qp;
        aq[m][1] = *(const bf16x8*)(qp + 32);
    }

    // staging addresses (kv-invariant): chunk ids sc, sc+64 per array
    const int sc = wave * 128 + lane;
    int srow[2], scol[2];
    srow[0] = sc >> 3;        srow[1] = (sc + 64) >> 3;
    scol[0] = (sc & 7) ^ (srow[0] & 7);
    scol[1] = ((sc + 64) & 7) ^ (srow[1] & 7);
    // K permuted kv offset for a physical row r
    auto kvloc = [](int r) {
        const int w = r >> 5, rw = r & 31, r4 = rw & 15;
        return w * 32 + ((rw >> 4) << 2) + ((r4 >> 2) << 3) + (r4 & 3);
    };
    const bf16* kga = K + base_bh + (size_t)kvloc(srow[0]) * DIM + scol[0] * 8;
    const bf16* kgb = K + base_bh + (size_t)kvloc(srow[1]) * DIM + scol[1] * 8;
    const bf16* vga = Vt + base_v + (size_t)srow[0] * SEQ + scol[0] * 8;
    const bf16* vgb = Vt + base_v + (size_t)srow[1] * SEQ + scol[1] * 8;
    const int ldsa = (wave * 128) * 8, ldsb = (wave * 128 + 64) * 8;

    // LDS read offsets (kv-invariant): K frags per group g, V per (w,dt)
    int koa[4], kob[4], vo[2][4];
#pragma unroll
    for (int g = 0; g < 4; g++) {
        const int krow = g * 16 + l16;
        koa[g] = (krow * 8 + (quad ^ (krow & 7))) * 8;
        kob[g] = (krow * 8 + ((4 + quad) ^ (krow & 7))) * 8;
    }
#pragma unroll
    for (int w = 0; w < 2; w++)
#pragma unroll
        for (int dt = 0; dt < 4; dt++) {
            const int d = dt * 16 + l16;
            vo[w][dt] = d * 64 + ((4 * w + quad) ^ (d & 7)) * 8;
        }

    bf16x8 ones8;
#pragma unroll
    for (int i = 0; i < 8; i++) ones8[i] = (bf16)1.0f;

    floatx4 acc[4][4], accl[4];
#pragma unroll
    for (int m = 0; m < 4; m++) {
        accl[m] = zero4();
#pragma unroll
        for (int dt = 0; dt < 4; dt++) acc[m][dt] = zero4();
    }

    // prologue: stage tile 0 into buffer 0
    load_lds16(kga, &Ks[0][ldsa]);
    load_lds16(kgb, &Ks[0][ldsb]);
    load_lds16(vga, &Vs[0][ldsa]);
    load_lds16(vgb, &Vs[0][ldsb]);

    for (int it = 0; it < SEQ / 64; it++) {
        __syncthreads();  // drains staging issued last iter; readers done
        const int cur = it & 1;
        if (it + 1 < SEQ / 64) {
            const int nxt = cur ^ 1;
            const size_t kvn = (size_t)(it + 1) * 64;
            load_lds16(kga + kvn * DIM, &Ks[nxt][ldsa]);
            load_lds16(kgb + kvn * DIM, &Ks[nxt][ldsb]);
            load_lds16(vga + kvn, &Vs[nxt][ldsa]);
            load_lds16(vgb + kvn, &Vs[nxt][ldsb]);
        }

#pragma unroll
        for (int w = 0; w < 2; w++) {
            // K frags for groups 2w (even: k=8q..8q+3), 2w+1 (odd: 8q+4..7)
            const bf16x8 ke0 = *(const bf16x8*)&Ks[cur][koa[2 * w]];
            const bf16x8 ke1 = *(const bf16x8*)&Ks[cur][kob[2 * w]];
            const bf16x8 ko0 = *(const bf16x8*)&Ks[cur][koa[2 * w + 1]];
            const bf16x8 ko1 = *(const bf16x8*)&Ks[cur][kob[2 * w + 1]];
            bf16x8 pw[4];
            __builtin_amdgcn_s_setprio(1);
#pragma unroll
            for (int m = 0; m < 4; m++) {
                floatx4 sa = zero4(), sb = zero4();
                sa = __builtin_amdgcn_mfma_f32_16x16x32_bf16(ke0, aq[m][0], sa, 0, 0, 0);
                sa = __builtin_amdgcn_mfma_f32_16x16x32_bf16(ke1, aq[m][1], sa, 0, 0, 0);
                sb = __builtin_amdgcn_mfma_f32_16x16x32_bf16(ko0, aq[m][0], sb, 0, 0, 0);
                sb = __builtin_amdgcn_mfma_f32_16x16x32_bf16(ko1, aq[m][1], sb, 0, 0, 0);
                bf16x8 p;
#pragma unroll
                for (int i = 0; i < 4; i++) {
                    p[i]     = (bf16)__builtin_amdgcn_exp2f(sa[i]);
                    p[4 + i] = (bf16)__builtin_amdgcn_exp2f(sb[i]);
                }
                pw[m] = p;
            }
            __builtin_amdgcn_s_setprio(0);
            // V frags: b128, natural kv order
            bf16x8 vf[4];
#pragma unroll
            for (int dt = 0; dt < 4; dt++)
                vf[dt] = *(const bf16x8*)&Vs[cur][vo[w][dt]];
            __builtin_amdgcn_s_setprio(1);
#pragma unroll
            for (int m = 0; m < 4; m++) {
#pragma unroll
                for (int dt = 0; dt < 4; dt++)
                    acc[m][dt] = __builtin_amdgcn_mfma_f32_16x16x32_bf16(
                        pw[m], vf[dt], acc[m][dt], 0, 0, 0);
                accl[m] = __builtin_amdgcn_mfma_f32_16x16x32_bf16(
                    pw[m], ones8, accl[m], 0, 0, 0);
            }
            __builtin_amdgcn_s_setprio(0);
        }
    }

    // store: O rows q=qt+m*16+quad*4+i, cols dt*16+l16
#pragma unroll
    for (int m = 0; m < 4; m++) {
        float inv[4];
#pragma unroll
        for (int i = 0; i < 4; i++) inv[i] = 1.0f / accl[m][i];
        bf16* cp = Ctx + base_bh + (size_t)(qt + m * 16 + quad * 4) * DIM + l16;
#pragma unroll
        for (int i = 0; i < 4; i++)
#pragma unroll
            for (int dt = 0; dt < 4; dt++)
                cp[(size_t)i * DIM + dt * 16] = (bf16)(acc[m][dt][i] * inv[i]);
    }
}

// ---------------------------------------------------------------------------
extern "C" void kernel_launch(void* const* d_in, const int* in_sizes, int n_in,
                              void* d_out, int out_size, void* d_ws, size_t ws_size,
                              hipStream_t stream) {
    const float* X  = (const float*)d_in[0];
    const float* Wq = (const float*)d_in[1];
    const float* bq = (const float*)d_in[2];
    const float* Wk = (const float*)d_in[3];
    const float* bk = (const float*)d_in[4];
    const float* Wv = (const float*)d_in[5];
    const float* bv = (const float*)d_in[6];
    const float* Wo = (const float*)d_in[7];
    const float* bo = (const float*)d_in[8];
    float* out = (float*)d_out;

    const size_t MD = (size_t)MTOT * DIM;
    const size_t DD = (size_t)DIM * DIM;

    bf16* Xb  = (bf16*)d_ws;     // X bf16; reused as ctx after attention
    bf16* Qb  = Xb + MD;
    bf16* Kb  = Qb + MD;
    bf16* Vtb = Kb + MD;         // V transposed [B*H][DH][SEQ]
    bf16* Wqb = Vtb + MD;        // [Wq;Wk;Wv;Wo] rows contiguous
    bf16* Wob = Wqb + 3 * DD;
    if (ws_size < (MD * 4 + DD * 4) * sizeof(bf16)) return;

    cvt_all<<<(int)((MD + 4 * DD) / 4 / 256), 256, 0, stream>>>(
        X, Wq, Wk, Wv, Wo, Xb, Wqb);

    // 384 blocks x 512 threads: 32 m-tiles x {Q,K,V} x 4 n-tiles
    gemm_qkv<<<384, 512, 0, stream>>>(Xb, Wqb, bq, bk, bv, Qb, Kb, Vtb);

    // 512 blocks x 256 threads: XCD-swizzled 64 (b,h) x 8 q-blocks (256 rows)
    attn_kernel<<<NB * NH * (SEQ / 256), 256, 0, stream>>>(Qb, Kb, Vtb, Xb);

    gemm_out<<<dim3(8, MTOT / 128), 256, 0, stream>>>(Xb, Wob, bo, out);
}

// Round 4
// 257.581 us; speedup vs baseline: 1.0906x; 1.0119x over previous
//
#include <hip/hip_runtime.h>

// ---------------------------------------------------------------------------
// AttentionActPrune — full MHA forward. B=4, S=2048, H=16, DH=64, D=1024.
// fp32 in/out; threshold 2% of max|ref| -> bf16 MFMA compute.
// Pipeline: cvt_all -> merged QKV GEMM (256x256 tile, BK=32, 4-buffer 128KB
// LDS, counted-vmcnt, 1 barrier/K-tile) -> flash-attn (NEW: 4-buffer
// counted-vmcnt staging, raw s_barrier, cross-w QK/exp/PV software pipeline)
// -> GEMM out (128x128).
// ---------------------------------------------------------------------------

typedef __bf16 bf16;
typedef __bf16 bf16x8 __attribute__((ext_vector_type(8)));
typedef __bf16 bf16x4 __attribute__((ext_vector_type(4)));
typedef float  floatx4 __attribute__((ext_vector_type(4)));

#define NB   4
#define SEQ  2048
#define NH   16
#define DH   64
#define DIM  1024
#define MTOT (NB * SEQ)   // 8192

#define CEXP 0.18033688f   // (1/sqrt(DH)) * log2(e), folded into Q

__device__ __forceinline__ floatx4 zero4() {
    floatx4 z; z[0] = 0.f; z[1] = 0.f; z[2] = 0.f; z[3] = 0.f; return z;
}

__device__ __forceinline__ void load_lds16(const bf16* g, bf16* l) {
    __builtin_amdgcn_global_load_lds(
        (__attribute__((address_space(1))) void*)g,
        (__attribute__((address_space(3))) void*)l,
        16, 0, 0);
}

// ---------------------------------------------------------------------------
// fp32 -> bf16 converts: X (MD elems) then [Wq;Wk;Wv;Wo] (4*DD) in one grid.
// ---------------------------------------------------------------------------
__global__ __launch_bounds__(256) void cvt_all(const float* __restrict__ X,
                                               const float* __restrict__ w0,
                                               const float* __restrict__ w1,
                                               const float* __restrict__ w2,
                                               const float* __restrict__ w3,
                                               bf16* __restrict__ Xb,
                                               bf16* __restrict__ Wb) {
    const size_t MD = (size_t)MTOT * DIM;
    const size_t DD = (size_t)DIM * DIM;   // 2^20
    size_t i = ((size_t)blockIdx.x * 256 + threadIdx.x) * 4;
    float4 f; bf16* dst;
    if (i < MD) {
        f = *(const float4*)(X + i);
        dst = Xb + i;
    } else {
        size_t off = i - MD;
        int w = (int)(off >> 20);
        size_t wi = off & (DD - 1);
        const float* ws = (w == 0) ? w0 : (w == 1) ? w1 : (w == 2) ? w2 : w3;
        f = *(const float4*)(ws + wi);
        dst = Wb + off;
    }
    bf16x4 o;
    o[0] = (bf16)f.x; o[1] = (bf16)f.y; o[2] = (bf16)f.z; o[3] = (bf16)f.w;
    *(bf16x4*)dst = o;
}

// ---------------------------------------------------------------------------
// Merged QKV GEMM, 256x256 tiles, deep-pipelined, 1 barrier per K-tile.
// ---------------------------------------------------------------------------
#define QKV_TILE(T_, DO_STAGE_, WAITSTR_) do {                                 \
    const bf16* bA_ = smem + ((T_) & 3) * 16384;                               \
    const bf16* bB_ = bA_ + 8192;                                              \
    if (DO_STAGE_) {                                                           \
        bf16* sA_ = smem + (((T_) + 3) & 3) * 16384;                           \
        const int ko_ = ((T_) + 3) * 32;                                       \
        load_lds16(gA0 + ko_, sA_ + soff0);                                    \
        load_lds16(gA1 + ko_, sA_ + soff1);                                    \
        load_lds16(gB0 + ko_, sA_ + 8192 + soff0);                             \
        load_lds16(gB1 + ko_, sA_ + 8192 + soff1);                             \
    }                                                                          \
    bf16x8 afr_[4], bfg_[4];                                                   \
    _Pragma("unroll")                                                          \
    for (int mf = 0; mf < 4; mf++) afr_[mf] = *(const bf16x8*)(bA_ + aoff[mf]);\
    _Pragma("unroll")                                                          \
    for (int nf = 0; nf < 4; nf++) bfg_[nf] = *(const bf16x8*)(bB_ + boff[nf]);\
    __builtin_amdgcn_s_setprio(1);                                             \
    _Pragma("unroll")                                                          \
    for (int mf = 0; mf < 4; mf++)                                             \
        _Pragma("unroll")                                                      \
        for (int nf = 0; nf < 4; nf++)                                         \
            acc[mf][nf] = __builtin_amdgcn_mfma_f32_16x16x32_bf16(             \
                afr_[mf], bfg_[nf], acc[mf][nf], 0, 0, 0);                     \
    __builtin_amdgcn_s_setprio(0);                                             \
    _Pragma("unroll")                                                          \
    for (int mf = 0; mf < 4; mf++)                                             \
        afr_[mf] = *(const bf16x8*)(bA_ + aoff[4 + mf]);                       \
    __builtin_amdgcn_s_setprio(1);                                             \
    _Pragma("unroll")                                                          \
    for (int mf = 0; mf < 4; mf++)                                             \
        _Pragma("unroll")                                                      \
        for (int nf = 0; nf < 4; nf++)                                         \
            acc[4 + mf][nf] = __builtin_amdgcn_mfma_f32_16x16x32_bf16(         \
                afr_[mf], bfg_[nf], acc[4 + mf][nf], 0, 0, 0);                 \
    __builtin_amdgcn_s_setprio(0);                                             \
    asm volatile(WAITSTR_ ::: "memory");                                       \
    __builtin_amdgcn_s_barrier();                                              \
} while (0)

__global__ __launch_bounds__(512, 2) void gemm_qkv(const bf16* __restrict__ A,
                                                   const bf16* __restrict__ W,
                                                   const float* __restrict__ bq,
                                                   const float* __restrict__ bk,
                                                   const float* __restrict__ bv,
                                                   bf16* __restrict__ Qo,
                                                   bf16* __restrict__ Ko,
                                                   bf16* __restrict__ Vt) {
    __shared__ __align__(16) bf16 smem[4 * 16384];   // 128 KiB

    const int tid  = threadIdx.x;
    const int wave = tid >> 6, lane = tid & 63;
    const int quad = lane >> 4, l16 = lane & 15;
    const int wr = wave >> 2, wc = wave & 3;         // 2 x 4 wave grid

    // bijective XCD swizzle: 384 = 8 * 48
    const int wg = (blockIdx.x & 7) * 48 + (blockIdx.x >> 3);
    const int mt = wg / 12, inner = wg % 12;
    const int sel = inner >> 2, nt = inner & 3;      // 0=Q 1=K 2=V
    const int m0 = mt * 256, n0 = nt * 256;

    const bf16* Wsel = W + (size_t)(sel * DIM + n0) * DIM;
    const float* bias = (sel == 0) ? bq : (sel == 1) ? bk : bv;

    // ds_read fragment offsets (elements), T2-swizzled
    int aoff[8], boff[4];
#pragma unroll
    for (int mf = 0; mf < 8; mf++) {
        const int row = wr * 128 + mf * 16 + l16;
        aoff[mf] = row * 32 + ((quad ^ ((row >> 1) & 3)) * 8);
    }
#pragma unroll
    for (int nf = 0; nf < 4; nf++) {
        const int row = wc * 64 + nf * 16 + l16;
        boff[nf] = row * 32 + ((quad ^ ((row >> 1) & 3)) * 8);
    }

    // staging: per K-tile, A = 1024 chunks of 16B (2/thread), B likewise.
    const int c0 = tid, c1 = tid + 512;
    const int ra0 = c0 >> 2, qa0 = (c0 & 3) ^ ((ra0 >> 1) & 3);
    const int ra1 = c1 >> 2, qa1 = (c1 & 3) ^ ((ra1 >> 1) & 3);
    const bf16* gA0 = A + (size_t)(m0 + ra0) * DIM + qa0 * 8;
    const bf16* gA1 = A + (size_t)(m0 + ra1) * DIM + qa1 * 8;
    const bf16* gB0 = Wsel + (size_t)ra0 * DIM + qa0 * 8;
    const bf16* gB1 = Wsel + (size_t)ra1 * DIM + qa1 * 8;
    const int soff0 = (wave * 64) * 8;               // wave-uniform LDS bases
    const int soff1 = (512 + wave * 64) * 8;

    floatx4 acc[8][4];
#pragma unroll
    for (int mf = 0; mf < 8; mf++)
#pragma unroll
        for (int nf = 0; nf < 4; nf++) acc[mf][nf] = zero4();

    // prologue: stage K-tiles 0,1,2 into buffers 0,1,2
#pragma unroll
    for (int kt = 0; kt < 3; kt++) {
        bf16* sA = smem + kt * 16384;
        bf16* sB = sA + 8192;
        load_lds16(gA0 + kt * 32, sA + soff0);
        load_lds16(gA1 + kt * 32, sA + soff1);
        load_lds16(gB0 + kt * 32, sB + soff0);
        load_lds16(gB1 + kt * 32, sB + soff1);
    }
    asm volatile("s_waitcnt vmcnt(8)" ::: "memory");   // tile 0 landed
    __builtin_amdgcn_s_barrier();

    const int NT = DIM / 32;   // 32 K-tiles
#pragma unroll 1
    for (int t = 0; t < NT - 3; t++)
        QKV_TILE(t, true, "s_waitcnt vmcnt(8)");
    QKV_TILE(NT - 3, false, "s_waitcnt vmcnt(4)");
    QKV_TILE(NT - 2, false, "s_waitcnt vmcnt(0)");
    QKV_TILE(NT - 1, false, "s_waitcnt vmcnt(0)");

    if (sel < 2) {
        bf16* C = (sel == 0) ? Qo : Ko;
        const float scale = (sel == 0) ? CEXP : 1.0f;
#pragma unroll
        for (int mf = 0; mf < 8; mf++) {
            const int rbase = m0 + wr * 128 + mf * 16 + quad * 4;
#pragma unroll
            for (int nf = 0; nf < 4; nf++) {
                const int col = n0 + wc * 64 + nf * 16 + l16;
                const float bval = bias[col];
#pragma unroll
                for (int i = 0; i < 4; i++)
                    C[(size_t)(rbase + i) * DIM + col] =
                        (bf16)((acc[mf][nf][i] + bval) * scale);
            }
        }
    } else {
        // V: transpose 256x256 tile via 128KB LDS -> Vt[(b*NH+h)][d][s]
        const int b  = m0 >> 11;           // m0 / SEQ
        const int s0 = m0 & (SEQ - 1);
#pragma unroll
        for (int mf = 0; mf < 8; mf++) {
            const int mb = wr * 128 + mf * 16 + quad * 4;
#pragma unroll
            for (int nf = 0; nf < 4; nf++) {
                const int n_loc = wc * 64 + nf * 16 + l16;
                const float bval = bias[n0 + n_loc];
                bf16x4 pk;
#pragma unroll
                for (int i = 0; i < 4; i++) pk[i] = (bf16)(acc[mf][nf][i] + bval);
                const int e = n_loc * 256 + (((mb * 2) ^ ((n_loc & 7) << 4)) >> 1);
                *(bf16x4*)(smem + e) = pk;
            }
        }
        asm volatile("s_waitcnt lgkmcnt(0)" ::: "memory");
        __builtin_amdgcn_s_barrier();
#pragma unroll
        for (int p = 0; p < 16; p++) {
            const int c = p * 512 + tid;
            const int n_loc = c >> 5, mc = (c & 31) * 8;
            const int e = n_loc * 256 + (((mc * 2) ^ ((n_loc & 7) << 4)) >> 1);
            bf16x8 v = *(const bf16x8*)(smem + e);
            const int dg = n0 + n_loc;
            const int hh = dg >> 6, d = dg & 63;
            bf16* op = Vt + ((size_t)(b * NH + hh) * DH + d) * SEQ + s0 + mc;
            *(bf16x8*)op = v;
        }
    }
}

// ---------------------------------------------------------------------------
// Out-projection GEMM (fp32 out), 128x128 tiles.
// ---------------------------------------------------------------------------
__global__ __launch_bounds__(256) void gemm_out(const bf16* __restrict__ A,
                                                const bf16* __restrict__ W,
                                                const float* __restrict__ bias,
                                                float* __restrict__ C) {
    __shared__ __align__(16) bf16 As[128 * 32];
    __shared__ __align__(16) bf16 Bs[128 * 32];

    const int tid  = threadIdx.x;
    const int wave = tid >> 6, lane = tid & 63;
    const int quad = lane >> 4, l16 = lane & 15;
    const int m0 = blockIdx.y * 128, n0 = blockIdx.x * 128;
    const int wm = (wave & 1) * 64, wn = (wave >> 1) * 64;

    floatx4 acc[4][4];
#pragma unroll
    for (int mi = 0; mi < 4; mi++)
#pragma unroll
        for (int ni = 0; ni < 4; ni++) acc[mi][ni] = zero4();

    for (int k0 = 0; k0 < DIM; k0 += 32) {
        __syncthreads();
#pragma unroll
        for (int i = 0; i < 2; i++) {
            const int cb = wave * 128 + i * 64;
            const int c  = cb + lane;
            const int row = c >> 2;
            const int kc  = (c & 3) * 8;
            load_lds16(A + (size_t)(m0 + row) * DIM + k0 + kc, &As[cb * 8]);
            load_lds16(W + (size_t)(n0 + row) * DIM + k0 + kc, &Bs[cb * 8]);
        }
        __syncthreads();

        bf16x8 af[4], bfr[4];
#pragma unroll
        for (int mi = 0; mi < 4; mi++)
            af[mi] = *(const bf16x8*)&As[(wm + mi * 16 + l16) * 32 + quad * 8];
#pragma unroll
        for (int ni = 0; ni < 4; ni++)
            bfr[ni] = *(const bf16x8*)&Bs[(wn + ni * 16 + l16) * 32 + quad * 8];
#pragma unroll
        for (int mi = 0; mi < 4; mi++)
#pragma unroll
            for (int ni = 0; ni < 4; ni++)
                acc[mi][ni] = __builtin_amdgcn_mfma_f32_16x16x32_bf16(
                    af[mi], bfr[ni], acc[mi][ni], 0, 0, 0);
    }

#pragma unroll
    for (int mi = 0; mi < 4; mi++) {
        const int rbase = m0 + wm + mi * 16 + quad * 4;
#pragma unroll
        for (int ni = 0; ni < 4; ni++) {
            const int col = n0 + wn + ni * 16 + l16;
            const float bval = bias[col];
#pragma unroll
            for (int i = 0; i < 4; i++)
                C[(size_t)(rbase + i) * DIM + col] = acc[mi][ni][i] + bval;
        }
    }
}

// ---------------------------------------------------------------------------
// Flash attention: 4-wave blocks = 256 q rows of one (b,h), 64 q/wave.
// NEW (R4): 4-buffer counted-vmcnt staging (stage t+3 during t, vmcnt(8)
// never 0 mid-loop, raw s_barrier — kills the per-tile vmcnt(0) drain
// convoy) + cross-w software pipeline: [QK(w0)] [frags(w1,w0V) issued]
// [exp(w0) || QK(w1)] [PV(w0) || exp(w1)] [PV(w1)] so MFMA and VALU
// streams are adjacent/independent for the scheduler.
// K rows staged PERMUTED within each 32-kv window so PV runs at K=32;
// V staged in natural [d][s] order. Q pre-scaled by CEXP -> P = exp2(z).
// ---------------------------------------------------------------------------
#define ATTN_MFMA(A_, B_, C_) __builtin_amdgcn_mfma_f32_16x16x32_bf16(A_, B_, C_, 0, 0, 0)

#define ATTN_TILE(T_, DO_STAGE_, DO_WAIT_, WAITSTR_) do {                      \
    const int cur_ = (T_) & 3;                                                 \
    if (DO_STAGE_) {                                                           \
        const int nb_ = ((T_) + 3) & 3;                                        \
        const size_t kvn_ = (size_t)((T_) + 3) * 64;                           \
        load_lds16(kga + kvn_ * DIM, &Ks[nb_][ldsa]);                          \
        load_lds16(kgb + kvn_ * DIM, &Ks[nb_][ldsb]);                          \
        load_lds16(vga + kvn_, &Vs[nb_][ldsa]);                                \
        load_lds16(vgb + kvn_, &Vs[nb_][ldsb]);                                \
    }                                                                          \
    /* K frags w0 + QK(w0) */                                                  \
    bf16x8 ke0_ = *(const bf16x8*)&Ks[cur_][koa[0]];                           \
    bf16x8 ke1_ = *(const bf16x8*)&Ks[cur_][kob[0]];                           \
    bf16x8 ko0_ = *(const bf16x8*)&Ks[cur_][koa[1]];                           \
    bf16x8 ko1_ = *(const bf16x8*)&Ks[cur_][kob[1]];                           \
    floatx4 sa0_[4], sb0_[4];                                                  \
    _Pragma("unroll")                                                          \
    for (int m = 0; m < 4; m++) {                                              \
        floatx4 sa = zero4(), sb = zero4();                                    \
        sa = ATTN_MFMA(ke0_, aq[m][0], sa);                                    \
        sa = ATTN_MFMA(ke1_, aq[m][1], sa);                                    \
        sb = ATTN_MFMA(ko0_, aq[m][0], sb);                                    \
        sb = ATTN_MFMA(ko1_, aq[m][1], sb);                                    \
        sa0_[m] = sa; sb0_[m] = sb;                                            \
    }                                                                          \
    /* issue K frags w1 + V frags w0 early (latency hides under exp(w0)) */    \
    bf16x8 kf1_[4];                                                            \
    kf1_[0] = *(const bf16x8*)&Ks[cur_][koa[2]];                               \
    kf1_[1] = *(const bf16x8*)&Ks[cur_][kob[2]];                               \
    kf1_[2] = *(const bf16x8*)&Ks[cur_][koa[3]];                               \
    kf1_[3] = *(const bf16x8*)&Ks[cur_][kob[3]];                               \
    bf16x8 vf0_[4];                                                            \
    _Pragma("unroll")                                                          \
    for (int dt = 0; dt < 4; dt++)                                             \
        vf0_[dt] = *(const bf16x8*)&Vs[cur_][vo[0][dt]];                       \
    /* exp(w0) -> pw0 (VALU)  [independent of QK(w1) MFMAs below] */           \
    bf16x8 pw0_[4];                                                            \
    _Pragma("unroll")                                                          \
    for (int m = 0; m < 4; m++) {                                              \
        bf16x8 p;                                                              \
        _Pragma("unroll")                                                      \
        for (int i = 0; i < 4; i++) {                                          \
            p[i]     = (bf16)__builtin_amdgcn_exp2f(sa0_[m][i]);               \
            p[4 + i] = (bf16)__builtin_amdgcn_exp2f(sb0_[m][i]);               \
        }                                                                      \
        pw0_[m] = p;                                                           \
    }                                                                          \
    /* QK(w1) */                                                               \
    floatx4 sa1_[4], sb1_[4];                                                  \
    _Pragma("unroll")                                                          \
    for (int m = 0; m < 4; m++) {                                              \
        floatx4 sa = zero4(), sb = zero4();                                    \
        sa = ATTN_MFMA(kf1_[0], aq[m][0], sa);                                 \
        sa = ATTN_MFMA(kf1_[1], aq[m][1], sa);                                 \
        sb = ATTN_MFMA(kf1_[2], aq[m][0], sb);                                 \
        sb = ATTN_MFMA(kf1_[3], aq[m][1], sb);                                 \
        sa1_[m] = sa; sb1_[m] = sb;                                            \
    }                                                                          \
    /* PV(w0) MFMAs  ||  exp(w1) VALU (independent, adjacent) */               \
    bf16x8 vf1_[4];                                                            \
    _Pragma("unroll")                                                          \
    for (int dt = 0; dt < 4; dt++)                                             \
        vf1_[dt] = *(const bf16x8*)&Vs[cur_][vo[1][dt]];                       \
    bf16x8 pw1_[4];                                                            \
    _Pragma("unroll")                                                          \
    for (int m = 0; m < 4; m++) {                                              \
        _Pragma("unroll")                                                      \
        for (int dt = 0; dt < 4; dt++)                                         \
            acc[m][dt] = ATTN_MFMA(pw0_[m], vf0_[dt], acc[m][dt]);             \
        accl[m] = ATTN_MFMA(pw0_[m], ones8, accl[m]);                          \
        bf16x8 p;                                                              \
        _Pragma("unroll")                                                      \
        for (int i = 0; i < 4; i++) {                                          \
            p[i]     = (bf16)__builtin_amdgcn_exp2f(sa1_[m][i]);               \
            p[4 + i] = (bf16)__builtin_amdgcn_exp2f(sb1_[m][i]);               \
        }                                                                      \
        pw1_[m] = p;                                                           \
    }                                                                          \
    /* PV(w1) */                                                               \
    _Pragma("unroll")                                                          \
    for (int m = 0; m < 4; m++) {                                              \
        _Pragma("unroll")                                                      \
        for (int dt = 0; dt < 4; dt++)                                         \
            acc[m][dt] = ATTN_MFMA(pw1_[m], vf1_[dt], acc[m][dt]);             \
        accl[m] = ATTN_MFMA(pw1_[m], ones8, accl[m]);                          \
    }                                                                          \
    if (DO_WAIT_) asm volatile(WAITSTR_ ::: "memory");                         \
    __builtin_amdgcn_s_barrier();                                              \
} while (0)

__global__ __launch_bounds__(256, 2) void attn_kernel(const bf16* __restrict__ Q,
                                                      const bf16* __restrict__ K,
                                                      const bf16* __restrict__ Vt,
                                                      bf16* __restrict__ Ctx) {
    __shared__ __align__(16) bf16 Ks[4][64 * 64];  // 4-deep, swizzled, kv-permuted
    __shared__ __align__(16) bf16 Vs[4][64 * 64];  // 4-deep, swizzled, natural order

    const int tid  = threadIdx.x;
    const int wave = tid >> 6, lane = tid & 63;
    const int quad = lane >> 4, l16 = lane & 15;
    // XCD-aware swizzle (512 blocks, 8 XCDs): 8 bh per XCD
    const int xcd = blockIdx.x & 7;
    const int j   = blockIdx.x >> 3;        // 0..63
    const int bh  = xcd * 8 + (j >> 3);     // b*NH + h
    const int qb  = j & 7;                  // 256-row q block
    const int b   = bh >> 4, h = bh & 15;

    const size_t base_bh = (size_t)b * SEQ * DIM + (size_t)h * DH;
    const size_t base_v  = (size_t)bh * DH * SEQ;
    const int qt = qb * 256 + wave * 64;    // wave's 64 q rows

    // Q frags (B-operand of swapped QK MFMA): 4 m-subtiles x 2 d-halves
    bf16x8 aq[4][2];
#pragma unroll
    for (int m = 0; m < 4; m++) {
        const bf16* qp = Q + base_bh + (size_t)(qt + m * 16 + l16) * DIM + quad * 8;
        aq[m][0] = *(const bf16x8*)qp;
        aq[m][1] = *(const bf16x8*)(qp + 32);
    }

    // staging addresses (kv-invariant): chunk ids sc, sc+64 per array
    const int sc = wave * 128 + lane;
    int srow[2], scol[2];
    srow[0] = sc >> 3;        srow[1] = (sc + 64) >> 3;
    scol[0] = (sc & 7) ^ (srow[0] & 7);
    scol[1] = ((sc + 64) & 7) ^ (srow[1] & 7);
    // K permuted kv offset for a physical row r
    auto kvloc = [](int r) {
        const int w = r >> 5, rw = r & 31, r4 = rw & 15;
        return w * 32 + ((rw >> 4) << 2) + ((r4 >> 2) << 3) + (r4 & 3);
    };
    const bf16* kga = K + base_bh + (size_t)kvloc(srow[0]) * DIM + scol[0] * 8;
    const bf16* kgb = K + base_bh + (size_t)kvloc(srow[1]) * DIM + scol[1] * 8;
    const bf16* vga = Vt + base_v + (size_t)srow[0] * SEQ + scol[0] * 8;
    const bf16* vgb = Vt + base_v + (size_t)srow[1] * SEQ + scol[1] * 8;
    const int ldsa = (wave * 128) * 8, ldsb = (wave * 128 + 64) * 8;

    // LDS read offsets (kv-invariant): K frags per group g, V per (w,dt)
    int koa[4], kob[4], vo[2][4];
#pragma unroll
    for (int g = 0; g < 4; g++) {
        const int krow = g * 16 + l16;
        koa[g] = (krow * 8 + (quad ^ (krow & 7))) * 8;
        kob[g] = (krow * 8 + ((4 + quad) ^ (krow & 7))) * 8;
    }
#pragma unroll
    for (int w = 0; w < 2; w++)
#pragma unroll
        for (int dt = 0; dt < 4; dt++) {
            const int d = dt * 16 + l16;
            vo[w][dt] = d * 64 + ((4 * w + quad) ^ (d & 7)) * 8;
        }

    bf16x8 ones8;
#pragma unroll
    for (int i = 0; i < 8; i++) ones8[i] = (bf16)1.0f;

    floatx4 acc[4][4], accl[4];
#pragma unroll
    for (int m = 0; m < 4; m++) {
        accl[m] = zero4();
#pragma unroll
        for (int dt = 0; dt < 4; dt++) acc[m][dt] = zero4();
    }

    // prologue: stage tiles 0,1,2 into buffers 0,1,2 (tile-major order)
#pragma unroll
    for (int kt = 0; kt < 3; kt++) {
        const size_t kvn = (size_t)kt * 64;
        load_lds16(kga + kvn * DIM, &Ks[kt][ldsa]);
        load_lds16(kgb + kvn * DIM, &Ks[kt][ldsb]);
        load_lds16(vga + kvn, &Vs[kt][ldsa]);
        load_lds16(vgb + kvn, &Vs[kt][ldsb]);
    }
    asm volatile("s_waitcnt vmcnt(8)" ::: "memory");   // tile 0 landed
    __builtin_amdgcn_s_barrier();

    const int NT = SEQ / 64;   // 32
#pragma unroll 1
    for (int t = 0; t < NT - 3; t++)
        ATTN_TILE(t, true, true, "s_waitcnt vmcnt(8)");
    ATTN_TILE(NT - 3, false, true, "s_waitcnt vmcnt(4)");
    ATTN_TILE(NT - 2, false, true, "s_waitcnt vmcnt(0)");
    ATTN_TILE(NT - 1, false, false, "");

    // store: O rows q=qt+m*16+quad*4+i, cols dt*16+l16
#pragma unroll
    for (int m = 0; m < 4; m++) {
        float inv[4];
#pragma unroll
        for (int i = 0; i < 4; i++) inv[i] = 1.0f / accl[m][i];
        bf16* cp = Ctx + base_bh + (size_t)(qt + m * 16 + quad * 4) * DIM + l16;
#pragma unroll
        for (int i = 0; i < 4; i++)
#pragma unroll
            for (int dt = 0; dt < 4; dt++)
                cp[(size_t)i * DIM + dt * 16] = (bf16)(acc[m][dt][i] * inv[i]);
    }
}

// ---------------------------------------------------------------------------
extern "C" void kernel_launch(void* const* d_in, const int* in_sizes, int n_in,
                              void* d_out, int out_size, void* d_ws, size_t ws_size,
                              hipStream_t stream) {
    const float* X  = (const float*)d_in[0];
    const float* Wq = (const float*)d_in[1];
    const float* bq = (const float*)d_in[2];
    const float* Wk = (const float*)d_in[3];
    const float* bk = (const float*)d_in[4];
    const float* Wv = (const float*)d_in[5];
    const float* bv = (const float*)d_in[6];
    const float* Wo = (const float*)d_in[7];
    const float* bo = (const float*)d_in[8];
    float* out = (float*)d_out;

    const size_t MD = (size_t)MTOT * DIM;
    const size_t DD = (size_t)DIM * DIM;

    bf16* Xb  = (bf16*)d_ws;     // X bf16; reused as ctx after attention
    bf16* Qb  = Xb + MD;
    bf16* Kb  = Qb + MD;
    bf16* Vtb = Kb + MD;         // V transposed [B*H][DH][SEQ]
    bf16* Wqb = Vtb + MD;        // [Wq;Wk;Wv;Wo] rows contiguous
    bf16* Wob = Wqb + 3 * DD;
    if (ws_size < (MD * 4 + DD * 4) * sizeof(bf16)) return;

    cvt_all<<<(int)((MD + 4 * DD) / 4 / 256), 256, 0, stream>>>(
        X, Wq, Wk, Wv, Wo, Xb, Wqb);

    // 384 blocks x 512 threads: 32 m-tiles x {Q,K,V} x 4 n-tiles
    gemm_qkv<<<384, 512, 0, stream>>>(Xb, Wqb, bq, bk, bv, Qb, Kb, Vtb);

    // 512 blocks x 256 threads: XCD-swizzled 64 (b,h) x 8 q-blocks (256 rows)
    attn_kernel<<<NB * NH * (SEQ / 256), 256, 0, stream>>>(Qb, Kb, Vtb, Xb);

    gemm_out<<<dim3(8, MTOT / 128), 256, 0, stream>>>(Xb, Wob, bo, out);
}